// Round 6
// baseline (1102.982 us; speedup 1.0000x reference)
//
#include <hip/hip_runtime.h>

#define NODES  50000
#define EDGES  800000
#define GRAPHS 1024
#define P      200      // uniform row pitch (floats) for node-feature buffers

// ---------------------------------------------------------------------------
// CSR build
// ---------------------------------------------------------------------------
__global__ void hist_kernel(const int* __restrict__ dst, int* __restrict__ deg) {
    int e = blockIdx.x * blockDim.x + threadIdx.x;
    if (e < EDGES) atomicAdd(&deg[dst[e]], 1);
}

__global__ void scan_kernel(const int* __restrict__ deg,
                            int* __restrict__ rowstart, int* __restrict__ cursor) {
    __shared__ int part[1024];
    int t = threadIdx.x;
    const int CH = (NODES + 1023) / 1024;   // 49
    int base = t * CH;
    int s = 0;
    for (int i = 0; i < CH; i++) {
        int n = base + i;
        if (n < NODES) s += deg[n];
    }
    part[t] = s;
    __syncthreads();
    for (int off = 1; off < 1024; off <<= 1) {
        int v = 0;
        if (t >= off) v = part[t - off];
        __syncthreads();
        if (t >= off) part[t] += v;
        __syncthreads();
    }
    int run = (t == 0) ? 0 : part[t - 1];
    for (int i = 0; i < CH; i++) {
        int n = base + i;
        if (n < NODES) {
            rowstart[n] = run;
            cursor[n]   = run;
            run += deg[n];
        }
    }
    if (t == 0) rowstart[NODES] = EDGES;
}

__global__ void scatter_kernel(const int* __restrict__ src, const int* __restrict__ dst,
                               int* __restrict__ cursor, int* __restrict__ csrc) {
    int e = blockIdx.x * blockDim.x + threadIdx.x;
    if (e < EDGES) {
        int p = atomicAdd(&cursor[dst[e]], 1);
        csrc[p] = src[e];
    }
}

// ---------------------------------------------------------------------------
// Weight pad: dst (KP x NP) = src (K x N), zero-filled beyond K rows / N cols
// ---------------------------------------------------------------------------
__global__ void pad_w_kernel(const float* __restrict__ src, int K, int N, int KP, int npshift,
                             float* __restrict__ dst) {
    int idx = blockIdx.x * blockDim.x + threadIdx.x;
    int NP = 1 << npshift;
    if (idx >= KP * NP) return;
    int k = idx >> npshift, n = idx & (NP - 1);
    dst[idx] = (k < K && n < N) ? src[k * N + n] : 0.0f;
}

// ---------------------------------------------------------------------------
// Aggregation, scalar path (D=114 packed input, D=64). Optional BN affine
// folded in: accumulates v*scale[c]+shift[c] == sum of BN(h_j).
// ---------------------------------------------------------------------------
template<int D, bool AFFINE>
__global__ void csr_agg(const float* __restrict__ feat, int fpitch,
                        const int* __restrict__ rowstart, const int* __restrict__ csrc,
                        const float* __restrict__ scale, const float* __restrict__ shift,
                        float* __restrict__ agg) {
    int wid  = (blockIdx.x * blockDim.x + threadIdx.x) >> 6;
    int lane = threadIdx.x & 63;
    if (wid >= NODES) return;
    constexpr int NI = (D + 63) / 64;
    float s[NI];
    float sc[NI], sh[NI];
#pragma unroll
    for (int i = 0; i < NI; i++) {
        s[i] = 0.0f;
        int c = lane + 64 * i;
        if (AFFINE && c < D) { sc[i] = scale[c]; sh[i] = shift[c]; }
    }
    int r0 = rowstart[wid], r1 = rowstart[wid + 1];
    for (int r = r0; r < r1; r++) {
        int sn = csrc[r];
        const float* fp = feat + (size_t)sn * fpitch;
#pragma unroll
        for (int i = 0; i < NI; i++) {
            int c = lane + 64 * i;
            if (c < D) {
                float v = fp[c];
                s[i] += AFFINE ? fmaf(v, sc[i], sh[i]) : v;
            }
        }
    }
    float* ap = agg + (size_t)wid * P;
#pragma unroll
    for (int i = 0; i < NI; i++) {
        int c = lane + 64 * i;
        if (c < D) ap[c] = s[i];
    }
}

// Vectorized aggregation for P-pitched features (whole 200-col row as 50
// float4 by lanes 0..49). Always applies BN affine. Pad cols carry garbage
// (finite), never consumed downstream.
__global__ void csr_agg_v4(const float* __restrict__ feat,
                           const int* __restrict__ rowstart, const int* __restrict__ csrc,
                           const float* __restrict__ scale, const float* __restrict__ shift,
                           float* __restrict__ agg) {
    int wid  = (blockIdx.x * blockDim.x + threadIdx.x) >> 6;
    int lane = threadIdx.x & 63;
    if (wid >= NODES) return;
    const float4* f4 = (const float4*)feat;
    float4 s = make_float4(0.f, 0.f, 0.f, 0.f);
    float4 sc = make_float4(0.f, 0.f, 0.f, 0.f), sh = sc;
    if (lane < 50) {
        sc = ((const float4*)scale)[lane];
        sh = ((const float4*)shift)[lane];
    }
    int r0 = rowstart[wid], r1 = rowstart[wid + 1];
    for (int r = r0; r < r1; r++) {
        int sn = csrc[r];
        if (lane < 50) {
            float4 v = f4[(size_t)sn * 50 + lane];
            s.x = fmaf(v.x, sc.x, s.x + sh.x);
            s.y = fmaf(v.y, sc.y, s.y + sh.y);
            s.z = fmaf(v.z, sc.z, s.z + sh.z);
            s.w = fmaf(v.w, sc.w, s.w + sh.w);
        }
    }
    if (lane < 50) ((float4*)agg)[(size_t)wid * 50 + lane] = s;
}

// ---------------------------------------------------------------------------
// GEMM: OUT[m][col0+n] = relu( (BN?(X[m]) + A2[m]) @ W + B ), optional BN
// stats epilogue. Block = ROWS rows x 64 cols; grid.y = col-blocks.
// A tile in LDS; W direct from global (L2-resident, zero-padded KP x NPtot).
// In-place OUT==A2 only used when grid.y==1 (block owns its rows: all reads
// of own rows precede epilogue writes).
// ---------------------------------------------------------------------------
template<int K, int N, int ROWS, bool ADD2, bool STATS, bool BNX>
__launch_bounds__(256)
__global__ void gemm_kernel(const float* __restrict__ X, int xpitch,
                            const float* __restrict__ A2,
                            const float* __restrict__ WP,   // KP x NPtot, zero-padded
                            const float* __restrict__ B,
                            const float* __restrict__ scale, const float* __restrict__ shift,
                            float* __restrict__ OUT,
                            float* __restrict__ gsum, float* __restrict__ gsq) {
    constexpr int NPT = ((N + 63) / 64) * 64;      // W pitch (256 or 64)
    constexpr int NPT4 = NPT / 4;
    constexpr int KT = 32;
    constexpr int NC = (K + KT - 1) / KT;
    constexpr int AS = KT + 4;                      // As row stride (bank-friendly)
    constexpr int RI = ROWS / 16;                   // rows per thread
    constexpr int AIT = (ROWS * KT) / 256;          // stage iters
    __shared__ __align__(16) float As[ROWS * AS];
    __shared__ float shSum[STATS ? 64 : 4];
    __shared__ float shSq [STATS ? 64 : 4];

    const int tid = threadIdx.x;
    const int tx = tid & 15, ty = tid >> 4;
    const int node0 = blockIdx.x * ROWS;
    const int col0  = blockIdx.y * 64;
    const float4* __restrict__ W4 = (const float4*)WP;
    const int c4 = (col0 >> 2) + tx;

    if (STATS && tid < 64) { shSum[tid] = 0.0f; shSq[tid] = 0.0f; }

    float acc[RI][4];
    {
        int nb = col0 + tx * 4;
        float bv[4];
#pragma unroll
        for (int e = 0; e < 4; e++) bv[e] = (nb + e < N) ? B[nb + e] : 0.0f;
#pragma unroll
        for (int i = 0; i < RI; i++)
#pragma unroll
            for (int e = 0; e < 4; e++) acc[i][e] = bv[e];
    }

    for (int c = 0; c < NC; c++) {
        const int kbase = c * KT;
        // ---- stage A chunk ----
#pragma unroll
        for (int it = 0; it < AIT; it++) {
            int idx = tid + 256 * it;
            int r = idx >> 5, cc = idx & 31;
            int gn = node0 + r, gk = kbase + cc;
            float v = 0.0f;
            if (gn < NODES && gk < K) {
                v = X[(size_t)gn * xpitch + gk];
                if (BNX) v = fmaf(v, scale[gk], shift[gk]);
                if (ADD2) v += A2[(size_t)gn * P + gk];
            }
            As[r * AS + cc] = v;
        }
        __syncthreads();

        // ---- compute: A from LDS, W from global (L2) ----
#pragma unroll
        for (int kk = 0; kk < KT; kk += 4) {
            float a[RI][4];
#pragma unroll
            for (int i = 0; i < RI; i++) {
                float4 av = *(const float4*)&As[(ty + 16 * i) * AS + kk];
                a[i][0] = av.x; a[i][1] = av.y; a[i][2] = av.z; a[i][3] = av.w;
            }
#pragma unroll
            for (int q = 0; q < 4; q++) {
                const int gk = kbase + kk + q;
                float4 w = W4[gk * NPT4 + c4];
#pragma unroll
                for (int i = 0; i < RI; i++) {
                    acc[i][0] = fmaf(a[i][q], w.x, acc[i][0]);
                    acc[i][1] = fmaf(a[i][q], w.y, acc[i][1]);
                    acc[i][2] = fmaf(a[i][q], w.z, acc[i][2]);
                    acc[i][3] = fmaf(a[i][q], w.w, acc[i][3]);
                }
            }
        }
        __syncthreads();
    }

    // ---- epilogue: relu, float4 store, stats ----
    {
        int nb = col0 + tx * 4;
        float rv[RI][4];
#pragma unroll
        for (int i = 0; i < RI; i++)
#pragma unroll
            for (int e = 0; e < 4; e++) rv[i][e] = fmaxf(acc[i][e], 0.0f);
#pragma unroll
        for (int i = 0; i < RI; i++) {
            int gn = node0 + ty + 16 * i;
            if (gn < NODES) {
                if (nb + 3 < N) {
                    *(float4*)&OUT[(size_t)gn * P + nb] =
                        make_float4(rv[i][0], rv[i][1], rv[i][2], rv[i][3]);
                } else {
#pragma unroll
                    for (int e = 0; e < 4; e++)
                        if (nb + e < N) OUT[(size_t)gn * P + nb + e] = rv[i][e];
                }
            }
        }
        if (STATS) {
#pragma unroll
            for (int e = 0; e < 4; e++) {
                int n = nb + e;
                if (n < N) {
                    float s = 0.0f, q = 0.0f;
#pragma unroll
                    for (int i = 0; i < RI; i++) {
                        if (node0 + ty + 16 * i < NODES) {
                            s += rv[i][e]; q += rv[i][e] * rv[i][e];
                        }
                    }
                    atomicAdd(&shSum[n - col0], s); atomicAdd(&shSq[n - col0], q);
                }
            }
        }
    }
    if (STATS) {
        __syncthreads();
        if (tid < 64) {
            int n = col0 + tid;
            if (n < N) {
                atomicAdd(&gsum[n], shSum[tid]);
                atomicAdd(&gsq[n], shSq[tid]);
            }
        }
    }
}

// ---------------------------------------------------------------------------
// BN finalize (scale/shift for folded apply)
// ---------------------------------------------------------------------------
template<int N>
__global__ void bn_finalize(const float* __restrict__ sum, const float* __restrict__ sq,
                            const float* __restrict__ gamma, const float* __restrict__ beta,
                            float* __restrict__ scale, float* __restrict__ shift) {
    int n = threadIdx.x;
    if (n < N) {
        float mean = sum[n] * (1.0f / NODES);
        float var  = sq[n] * (1.0f / NODES) - mean * mean;
        var = var < 0.0f ? 0.0f : var;
        float sc = gamma[n] * rsqrtf(var + 1e-5f);
        scale[n] = sc;
        shift[n] = beta[n] - mean * sc;
    }
}

// ---------------------------------------------------------------------------
// Pool (BN3 affine folded) + head MLP
// ---------------------------------------------------------------------------
__global__ void pool_kernel(const float* __restrict__ h, const int* __restrict__ batch,
                            const float* __restrict__ scale, const float* __restrict__ shift,
                            float* __restrict__ g) {
    int idx = blockIdx.x * blockDim.x + threadIdx.x;
    if (idx >= NODES * 32) return;
    int n = idx >> 5, f = idx & 31;
    float v = fmaf(h[(size_t)n * P + f], scale[f], shift[f]);
    atomicAdd(&g[batch[n] * 32 + f], v);
}

__global__ void head_kernel(const float* __restrict__ g,
                            const float* __restrict__ fw1, const float* __restrict__ fb1,
                            const float* __restrict__ fw2, const float* __restrict__ fb2,
                            const float* __restrict__ ow, const float* __restrict__ ob,
                            float* __restrict__ out) {
    int gi = blockIdx.x * blockDim.x + threadIdx.x;
    if (gi >= GRAPHS) return;
    float v[32];
#pragma unroll
    for (int k = 0; k < 32; k++) v[k] = g[gi * 32 + k];
    float a1[16];
#pragma unroll
    for (int o = 0; o < 16; o++) {
        float s = fb1[o];
#pragma unroll
        for (int k = 0; k < 32; k++) s = fmaf(v[k], fw1[k * 16 + o], s);
        a1[o] = s > 0.0f ? s : 0.0f;
    }
    float a2[8];
#pragma unroll
    for (int o = 0; o < 8; o++) {
        float s = fb2[o];
#pragma unroll
        for (int k = 0; k < 16; k++) s = fmaf(a1[k], fw2[k * 8 + o], s);
        a2[o] = s > 0.0f ? s : 0.0f;
    }
#pragma unroll
    for (int o = 0; o < 2; o++) {
        float s = ob[o];
#pragma unroll
        for (int k = 0; k < 8; k++) s = fmaf(a2[k], ow[k * 2 + o], s);
        out[gi * 2 + o] = s;
    }
}

// ---------------------------------------------------------------------------
extern "C" void kernel_launch(void* const* d_in, const int* in_sizes, int n_in,
                              void* d_out, int out_size, void* d_ws, size_t ws_size,
                              hipStream_t stream) {
    const float* x     = (const float*)d_in[0];
    const int*   ei    = (const int*)d_in[1];
    const int*   batch = (const int*)d_in[2];
    const float *w1a = (const float*)d_in[3],  *b1a = (const float*)d_in[4];
    const float *w1b = (const float*)d_in[5],  *b1b = (const float*)d_in[6];
    const float *g1  = (const float*)d_in[7],  *be1 = (const float*)d_in[8];
    const float *w2a = (const float*)d_in[9],  *b2a = (const float*)d_in[10];
    const float *w2b = (const float*)d_in[11], *b2b = (const float*)d_in[12];
    const float *g2  = (const float*)d_in[13], *be2 = (const float*)d_in[14];
    const float *w3a = (const float*)d_in[15], *b3a = (const float*)d_in[16];
    const float *w3b = (const float*)d_in[17], *b3b = (const float*)d_in[18];
    const float *g3  = (const float*)d_in[19], *be3 = (const float*)d_in[20];
    const float *fw1 = (const float*)d_in[21], *fb1 = (const float*)d_in[22];
    const float *fw2 = (const float*)d_in[23], *fb2 = (const float*)d_in[24];
    const float *ow  = (const float*)d_in[25], *ob  = (const float*)d_in[26];
    const int* src = ei;
    const int* dst = ei + EDGES;

    float* ws    = (float*)d_ws;
    float* b0    = ws;                                  // 50000 x 200
    float* b1    = ws + (size_t)NODES * P;              // 50000 x 200
    float* SUM   = ws + (size_t)2 * NODES * P;          // 256
    float* SQ    = SUM + 256;
    float* SCALE = SUM + 512;
    float* SHIFT = SUM + 768;
    float* G     = SUM + 1024;                          // 1024 x 32
    int*   deg      = (int*)(G + GRAPHS * 32);          // 50000
    int*   rowstart = deg + NODES;                      // 50001
    int*   cursor   = rowstart + NODES + 1;             // 50000
    int*   csrc     = cursor + NODES;                   // 800000
    float* WP1 = (float*)(csrc + EDGES);                // 128 x 256 (K-padded)
    float* WP2 = WP1 + 128 * 256;                       // 224 x 256
    float* WP3 = WP2 + 224 * 256;                       // 224 x 64
    float* WP4 = WP3 + 224 * 64;                        // 64 x 64
    float* WP5 = WP4 + 64 * 64;                         // 64 x 64
    float* WP6 = WP5 + 64 * 64;                         // 32 x 64
    float* out = (float*)d_out;

    const int GB64 = (NODES + 63) / 64;      // 782
    const int GB32 = (NODES + 31) / 32;      // 1563
    const int AB = (NODES * 64 + 255) / 256; // agg blocks (wave per node)
    const int EB = (EDGES + 255) / 256;

    // ---- weight padding (once per launch; K-padded to KT multiples) ----
    pad_w_kernel<<<(128 * 256 + 255) / 256, 256, 0, stream>>>(w1a, 114, 198, 128, 8, WP1);
    pad_w_kernel<<<(224 * 256 + 255) / 256, 256, 0, stream>>>(w1b, 198, 198, 224, 8, WP2);
    pad_w_kernel<<<(224 * 64 + 255) / 256, 256, 0, stream>>>(w2a, 198, 64, 224, 6, WP3);
    pad_w_kernel<<<(64 * 64 + 255) / 256, 256, 0, stream>>>(w2b, 64, 64, 64, 6, WP4);
    pad_w_kernel<<<(64 * 64 + 255) / 256, 256, 0, stream>>>(w3a, 64, 32, 64, 6, WP5);
    pad_w_kernel<<<(32 * 64 + 255) / 256, 256, 0, stream>>>(w3b, 32, 32, 32, 6, WP6);

    // ---- CSR build (shared by all 3 layers) ----
    hipMemsetAsync(deg, 0, NODES * sizeof(int), stream);
    hist_kernel<<<EB, 256, 0, stream>>>(dst, deg);
    scan_kernel<<<1, 1024, 0, stream>>>(deg, rowstart, cursor);
    scatter_kernel<<<EB, 256, 0, stream>>>(src, dst, cursor, csrc);

    // ---- layer 1 (114 -> 198 -> 198), split-N, ping-pong x,b0 -> b1 -> b0 ----
    csr_agg<114, false><<<AB, 256, 0, stream>>>(x, 114, rowstart, csrc, nullptr, nullptr, b0);
    gemm_kernel<114, 198, 64, true, false, false><<<dim3(GB64, 4), 256, 0, stream>>>(
        x, 114, b0, WP1, b1a, nullptr, nullptr, b1, nullptr, nullptr);
    hipMemsetAsync(SUM, 0, 512 * sizeof(float), stream);
    gemm_kernel<198, 198, 64, false, true, false><<<dim3(GB64, 4), 256, 0, stream>>>(
        b1, P, nullptr, WP2, b1b, nullptr, nullptr, b0, SUM, SQ);
    bn_finalize<198><<<1, 256, 0, stream>>>(SUM, SQ, g1, be1, SCALE, SHIFT);

    // ---- layer 2 (198 -> 64 -> 64); BN1 folded into agg + gemm stage ----
    csr_agg_v4<<<AB, 256, 0, stream>>>(b0, rowstart, csrc, SCALE, SHIFT, b1);
    gemm_kernel<198, 64, 32, true, false, true><<<dim3(GB32, 1), 256, 0, stream>>>(
        b0, P, b1, WP3, b2a, SCALE, SHIFT, b1, nullptr, nullptr);
    hipMemsetAsync(SUM, 0, 512 * sizeof(float), stream);
    gemm_kernel<64, 64, 32, false, true, false><<<dim3(GB32, 1), 256, 0, stream>>>(
        b1, P, nullptr, WP4, b2b, nullptr, nullptr, b0, SUM, SQ);
    bn_finalize<64><<<1, 256, 0, stream>>>(SUM, SQ, g2, be2, SCALE, SHIFT);

    // ---- layer 3 (64 -> 32 -> 32); BN2 folded ----
    csr_agg<64, true><<<AB, 256, 0, stream>>>(b0, P, rowstart, csrc, SCALE, SHIFT, b1);
    gemm_kernel<64, 32, 32, true, false, true><<<dim3(GB32, 1), 256, 0, stream>>>(
        b0, P, b1, WP5, b3a, SCALE, SHIFT, b1, nullptr, nullptr);
    hipMemsetAsync(SUM, 0, 512 * sizeof(float), stream);
    gemm_kernel<32, 32, 32, false, true, false><<<dim3(GB32, 1), 256, 0, stream>>>(
        b1, P, nullptr, WP6, b3b, nullptr, nullptr, b0, SUM, SQ);
    bn_finalize<32><<<1, 256, 0, stream>>>(SUM, SQ, g3, be3, SCALE, SHIFT);

    // ---- pool (BN3 folded) + head ----
    hipMemsetAsync(G, 0, GRAPHS * 32 * sizeof(float), stream);
    pool_kernel<<<(NODES * 32 + 255) / 256, 256, 0, stream>>>(b0, batch, SCALE, SHIFT, G);
    head_kernel<<<(GRAPHS + 255) / 256, 256, 0, stream>>>(G, fw1, fb1, fw2, fb2, ow, ob, out);
}

// Round 7
// 1063.006 us; speedup vs baseline: 1.0376x; 1.0376x over previous
//
#include <hip/hip_runtime.h>

#define NODES  50000
#define EDGES  800000
#define GRAPHS 1024
#define P      200      // uniform row pitch (floats) for node-feature buffers

// ---------------------------------------------------------------------------
// CSR build
// ---------------------------------------------------------------------------
__global__ void hist_kernel(const int* __restrict__ dst, int* __restrict__ deg) {
    int e = blockIdx.x * blockDim.x + threadIdx.x;
    if (e < EDGES) atomicAdd(&deg[dst[e]], 1);
}

__global__ void scan_kernel(const int* __restrict__ deg,
                            int* __restrict__ rowstart, int* __restrict__ cursor) {
    __shared__ int part[1024];
    int t = threadIdx.x;
    const int CH = (NODES + 1023) / 1024;   // 49
    int base = t * CH;
    int s = 0;
    for (int i = 0; i < CH; i++) {
        int n = base + i;
        if (n < NODES) s += deg[n];
    }
    part[t] = s;
    __syncthreads();
    for (int off = 1; off < 1024; off <<= 1) {
        int v = 0;
        if (t >= off) v = part[t - off];
        __syncthreads();
        if (t >= off) part[t] += v;
        __syncthreads();
    }
    int run = (t == 0) ? 0 : part[t - 1];
    for (int i = 0; i < CH; i++) {
        int n = base + i;
        if (n < NODES) {
            rowstart[n] = run;
            cursor[n]   = run;
            run += deg[n];
        }
    }
    if (t == 0) rowstart[NODES] = EDGES;
}

__global__ void scatter_kernel(const int* __restrict__ src, const int* __restrict__ dst,
                               int* __restrict__ cursor, int* __restrict__ csrc) {
    int e = blockIdx.x * blockDim.x + threadIdx.x;
    if (e < EDGES) {
        int p = atomicAdd(&cursor[dst[e]], 1);
        csrc[p] = src[e];
    }
}

// ---------------------------------------------------------------------------
// Weight pad: dst (KP x NP) = src (K x N), zero-filled beyond K rows / N cols
// ---------------------------------------------------------------------------
__global__ void pad_w_kernel(const float* __restrict__ src, int K, int N, int KP, int npshift,
                             float* __restrict__ dst) {
    int idx = blockIdx.x * blockDim.x + threadIdx.x;
    int NP = 1 << npshift;
    if (idx >= KP * NP) return;
    int k = idx >> npshift, n = idx & (NP - 1);
    dst[idx] = (k < K && n < N) ? src[k * N + n] : 0.0f;
}

// ---------------------------------------------------------------------------
// Aggregation, scalar path (D=114 packed input, D=64). Optional BN affine
// folded in: accumulates v*scale[c]+shift[c] == sum of BN(h_j).
// ---------------------------------------------------------------------------
template<int D, bool AFFINE>
__global__ void csr_agg(const float* __restrict__ feat, int fpitch,
                        const int* __restrict__ rowstart, const int* __restrict__ csrc,
                        const float* __restrict__ scale, const float* __restrict__ shift,
                        float* __restrict__ agg) {
    int wid  = (blockIdx.x * blockDim.x + threadIdx.x) >> 6;
    int lane = threadIdx.x & 63;
    if (wid >= NODES) return;
    constexpr int NI = (D + 63) / 64;
    float s[NI];
    float sc[NI], sh[NI];
#pragma unroll
    for (int i = 0; i < NI; i++) {
        s[i] = 0.0f;
        int c = lane + 64 * i;
        if (AFFINE && c < D) { sc[i] = scale[c]; sh[i] = shift[c]; }
    }
    int r0 = rowstart[wid], r1 = rowstart[wid + 1];
    for (int r = r0; r < r1; r++) {
        int sn = csrc[r];
        const float* fp = feat + (size_t)sn * fpitch;
#pragma unroll
        for (int i = 0; i < NI; i++) {
            int c = lane + 64 * i;
            if (c < D) {
                float v = fp[c];
                s[i] += AFFINE ? fmaf(v, sc[i], sh[i]) : v;
            }
        }
    }
    float* ap = agg + (size_t)wid * P;
#pragma unroll
    for (int i = 0; i < NI; i++) {
        int c = lane + 64 * i;
        if (c < D) ap[c] = s[i];
    }
}

// Vectorized aggregation for P-pitched features (whole 200-col row as 50
// float4 by lanes 0..49). Always applies BN affine. Pad cols carry garbage
// (finite), never consumed downstream.
__global__ void csr_agg_v4(const float* __restrict__ feat,
                           const int* __restrict__ rowstart, const int* __restrict__ csrc,
                           const float* __restrict__ scale, const float* __restrict__ shift,
                           float* __restrict__ agg) {
    int wid  = (blockIdx.x * blockDim.x + threadIdx.x) >> 6;
    int lane = threadIdx.x & 63;
    if (wid >= NODES) return;
    const float4* f4 = (const float4*)feat;
    float4 s = make_float4(0.f, 0.f, 0.f, 0.f);
    float4 sc = make_float4(0.f, 0.f, 0.f, 0.f), sh = sc;
    if (lane < 50) {
        sc = ((const float4*)scale)[lane];
        sh = ((const float4*)shift)[lane];
    }
    int r0 = rowstart[wid], r1 = rowstart[wid + 1];
    for (int r = r0; r < r1; r++) {
        int sn = csrc[r];
        if (lane < 50) {
            float4 v = f4[(size_t)sn * 50 + lane];
            s.x = fmaf(v.x, sc.x, s.x + sh.x);
            s.y = fmaf(v.y, sc.y, s.y + sh.y);
            s.z = fmaf(v.z, sc.z, s.z + sh.z);
            s.w = fmaf(v.w, sc.w, s.w + sh.w);
        }
    }
    if (lane < 50) ((float4*)agg)[(size_t)wid * 50 + lane] = s;
}

// ---------------------------------------------------------------------------
// GEMM: OUT[m][n] = relu( (BN?(X[m]) + A2[m]) @ W + B ), optional BN-stat
// epilogue. Block = ROWS rows x NP cols (NO column split -> A read exactly
// once). ROWS=32 doubles the grid vs r5 (1563 blocks = 6 blocks/CU of work);
// launch_bounds(256,4) caps VGPR at 128 so 4 blocks/CU stay resident.
// A tile in LDS; W direct from global (L2-resident, zero-padded KP x NP).
// In-place OUT==A2 safe: block owns its rows; reads precede epilogue writes.
// ---------------------------------------------------------------------------
template<int K, int N, int ROWS, bool ADD2, bool STATS, bool BNX>
__launch_bounds__(256, 4)
__global__ void gemm_kernel(const float* __restrict__ X, int xpitch,
                            const float* __restrict__ A2,
                            const float* __restrict__ WP,   // KP x NP, zero-padded
                            const float* __restrict__ B,
                            const float* __restrict__ scale, const float* __restrict__ shift,
                            float* __restrict__ OUT,
                            float* __restrict__ gsum, float* __restrict__ gsq) {
    constexpr int NP = ((N + 63) / 64) * 64;       // 64 or 256
    constexpr int NP4 = NP / 4;
    constexpr int G  = NP / 64;
    constexpr int KT = 32;
    constexpr int NC = (K + KT - 1) / KT;
    constexpr int AS = KT + 4;                      // As row stride (bank-friendly)
    constexpr int RI = ROWS / 16;                   // rows per thread
    constexpr int AIT = (ROWS * KT) / 256;          // stage iters
    __shared__ __align__(16) float As[ROWS * AS];
    __shared__ float shSum[STATS ? NP : 4];
    __shared__ float shSq [STATS ? NP : 4];

    const int tid = threadIdx.x;
    const int tx = tid & 15, ty = tid >> 4;
    const int node0 = blockIdx.x * ROWS;
    const float4* __restrict__ W4 = (const float4*)WP;

    if (STATS && tid < NP) { shSum[tid] = 0.0f; shSq[tid] = 0.0f; }

    float acc[RI][G][4];
#pragma unroll
    for (int g = 0; g < G; g++) {
#pragma unroll
        for (int e = 0; e < 4; e++) {
            int n = tx * 4 + 64 * g + e;
            float bv = (n < N) ? B[n] : 0.0f;
#pragma unroll
            for (int i = 0; i < RI; i++) acc[i][g][e] = bv;
        }
    }

    for (int c = 0; c < NC; c++) {
        const int kbase = c * KT;
        // ---- stage A chunk: rows [node0,node0+ROWS), cols [kbase,kbase+KT) ----
#pragma unroll
        for (int it = 0; it < AIT; it++) {
            int idx = tid + 256 * it;
            int r = idx >> 5, cc = idx & 31;
            int gn = node0 + r, gk = kbase + cc;
            float v = 0.0f;
            if (gn < NODES && gk < K) {
                v = X[(size_t)gn * xpitch + gk];
                if (BNX) v = fmaf(v, scale[gk], shift[gk]);
                if (ADD2) v += A2[(size_t)gn * P + gk];
            }
            As[r * AS + cc] = v;
        }
        __syncthreads();

        // ---- compute: A from LDS, W from global (L2) ----
#pragma unroll
        for (int kk = 0; kk < KT; kk += 4) {
            float a[RI][4];
#pragma unroll
            for (int i = 0; i < RI; i++) {
                float4 av = *(const float4*)&As[(ty + 16 * i) * AS + kk];
                a[i][0] = av.x; a[i][1] = av.y; a[i][2] = av.z; a[i][3] = av.w;
            }
#pragma unroll
            for (int q = 0; q < 4; q++) {
                const int gk = kbase + kk + q;
#pragma unroll
                for (int g = 0; g < G; g++) {
                    float4 w = W4[gk * NP4 + tx + 16 * g];
#pragma unroll
                    for (int i = 0; i < RI; i++) {
                        acc[i][g][0] = fmaf(a[i][q], w.x, acc[i][g][0]);
                        acc[i][g][1] = fmaf(a[i][q], w.y, acc[i][g][1]);
                        acc[i][g][2] = fmaf(a[i][q], w.z, acc[i][g][2]);
                        acc[i][g][3] = fmaf(a[i][q], w.w, acc[i][g][3]);
                    }
                }
            }
        }
        __syncthreads();
    }

    // ---- epilogue: relu, float4 store, stats ----
#pragma unroll
    for (int g = 0; g < G; g++) {
        int nb = tx * 4 + 64 * g;
        float rv[RI][4];
#pragma unroll
        for (int i = 0; i < RI; i++)
#pragma unroll
            for (int e = 0; e < 4; e++) rv[i][e] = fmaxf(acc[i][g][e], 0.0f);
#pragma unroll
        for (int i = 0; i < RI; i++) {
            int gn = node0 + ty + 16 * i;
            if (gn < NODES) {
                if (nb + 3 < N) {
                    *(float4*)&OUT[(size_t)gn * P + nb] =
                        make_float4(rv[i][0], rv[i][1], rv[i][2], rv[i][3]);
                } else {
#pragma unroll
                    for (int e = 0; e < 4; e++)
                        if (nb + e < N) OUT[(size_t)gn * P + nb + e] = rv[i][e];
                }
            }
        }
        if (STATS) {
#pragma unroll
            for (int e = 0; e < 4; e++) {
                int n = nb + e;
                if (n < N) {
                    float s = 0.0f, q = 0.0f;
#pragma unroll
                    for (int i = 0; i < RI; i++) {
                        if (node0 + ty + 16 * i < NODES) {
                            s += rv[i][e]; q += rv[i][e] * rv[i][e];
                        }
                    }
                    atomicAdd(&shSum[n], s); atomicAdd(&shSq[n], q);
                }
            }
        }
    }
    if (STATS) {
        __syncthreads();
        for (int n = tid; n < N; n += 256) {
            atomicAdd(&gsum[n], shSum[n]);
            atomicAdd(&gsq[n], shSq[n]);
        }
    }
}

// ---------------------------------------------------------------------------
// BN finalize (scale/shift for folded apply)
// ---------------------------------------------------------------------------
template<int N>
__global__ void bn_finalize(const float* __restrict__ sum, const float* __restrict__ sq,
                            const float* __restrict__ gamma, const float* __restrict__ beta,
                            float* __restrict__ scale, float* __restrict__ shift) {
    int n = threadIdx.x;
    if (n < N) {
        float mean = sum[n] * (1.0f / NODES);
        float var  = sq[n] * (1.0f / NODES) - mean * mean;
        var = var < 0.0f ? 0.0f : var;
        float sc = gamma[n] * rsqrtf(var + 1e-5f);
        scale[n] = sc;
        shift[n] = beta[n] - mean * sc;
    }
}

// ---------------------------------------------------------------------------
// Pool (BN3 affine folded) + head MLP
// ---------------------------------------------------------------------------
__global__ void pool_kernel(const float* __restrict__ h, const int* __restrict__ batch,
                            const float* __restrict__ scale, const float* __restrict__ shift,
                            float* __restrict__ g) {
    int idx = blockIdx.x * blockDim.x + threadIdx.x;
    if (idx >= NODES * 32) return;
    int n = idx >> 5, f = idx & 31;
    float v = fmaf(h[(size_t)n * P + f], scale[f], shift[f]);
    atomicAdd(&g[batch[n] * 32 + f], v);
}

__global__ void head_kernel(const float* __restrict__ g,
                            const float* __restrict__ fw1, const float* __restrict__ fb1,
                            const float* __restrict__ fw2, const float* __restrict__ fb2,
                            const float* __restrict__ ow, const float* __restrict__ ob,
                            float* __restrict__ out) {
    int gi = blockIdx.x * blockDim.x + threadIdx.x;
    if (gi >= GRAPHS) return;
    float v[32];
#pragma unroll
    for (int k = 0; k < 32; k++) v[k] = g[gi * 32 + k];
    float a1[16];
#pragma unroll
    for (int o = 0; o < 16; o++) {
        float s = fb1[o];
#pragma unroll
        for (int k = 0; k < 32; k++) s = fmaf(v[k], fw1[k * 16 + o], s);
        a1[o] = s > 0.0f ? s : 0.0f;
    }
    float a2[8];
#pragma unroll
    for (int o = 0; o < 8; o++) {
        float s = fb2[o];
#pragma unroll
        for (int k = 0; k < 16; k++) s = fmaf(a1[k], fw2[k * 8 + o], s);
        a2[o] = s > 0.0f ? s : 0.0f;
    }
#pragma unroll
    for (int o = 0; o < 2; o++) {
        float s = ob[o];
#pragma unroll
        for (int k = 0; k < 8; k++) s = fmaf(a2[k], ow[k * 2 + o], s);
        out[gi * 2 + o] = s;
    }
}

// ---------------------------------------------------------------------------
extern "C" void kernel_launch(void* const* d_in, const int* in_sizes, int n_in,
                              void* d_out, int out_size, void* d_ws, size_t ws_size,
                              hipStream_t stream) {
    const float* x     = (const float*)d_in[0];
    const int*   ei    = (const int*)d_in[1];
    const int*   batch = (const int*)d_in[2];
    const float *w1a = (const float*)d_in[3],  *b1a = (const float*)d_in[4];
    const float *w1b = (const float*)d_in[5],  *b1b = (const float*)d_in[6];
    const float *g1  = (const float*)d_in[7],  *be1 = (const float*)d_in[8];
    const float *w2a = (const float*)d_in[9],  *b2a = (const float*)d_in[10];
    const float *w2b = (const float*)d_in[11], *b2b = (const float*)d_in[12];
    const float *g2  = (const float*)d_in[13], *be2 = (const float*)d_in[14];
    const float *w3a = (const float*)d_in[15], *b3a = (const float*)d_in[16];
    const float *w3b = (const float*)d_in[17], *b3b = (const float*)d_in[18];
    const float *g3  = (const float*)d_in[19], *be3 = (const float*)d_in[20];
    const float *fw1 = (const float*)d_in[21], *fb1 = (const float*)d_in[22];
    const float *fw2 = (const float*)d_in[23], *fb2 = (const float*)d_in[24];
    const float *ow  = (const float*)d_in[25], *ob  = (const float*)d_in[26];
    const int* src = ei;
    const int* dst = ei + EDGES;

    float* ws    = (float*)d_ws;
    float* b0    = ws;                                  // 50000 x 200
    float* b1    = ws + (size_t)NODES * P;              // 50000 x 200
    float* SUM   = ws + (size_t)2 * NODES * P;          // 256
    float* SQ    = SUM + 256;
    float* SCALE = SUM + 512;
    float* SHIFT = SUM + 768;
    float* G     = SUM + 1024;                          // 1024 x 32
    int*   deg      = (int*)(G + GRAPHS * 32);          // 50000
    int*   rowstart = deg + NODES;                      // 50001
    int*   cursor   = rowstart + NODES + 1;             // 50000
    int*   csrc     = cursor + NODES;                   // 800000
    float* WP1 = (float*)(csrc + EDGES);                // 128 x 256 (K-padded)
    float* WP2 = WP1 + 128 * 256;                       // 224 x 256
    float* WP3 = WP2 + 224 * 256;                       // 224 x 64
    float* WP4 = WP3 + 224 * 64;                        // 64 x 64
    float* WP5 = WP4 + 64 * 64;                         // 64 x 64
    float* WP6 = WP5 + 64 * 64;                         // 32 x 64
    float* out = (float*)d_out;

    const int GB32 = (NODES + 31) / 32;      // 1563
    const int AB = (NODES * 64 + 255) / 256; // agg blocks (wave per node)
    const int EB = (EDGES + 255) / 256;

    // ---- weight padding (once per launch; K-padded to KT multiples) ----
    pad_w_kernel<<<(128 * 256 + 255) / 256, 256, 0, stream>>>(w1a, 114, 198, 128, 8, WP1);
    pad_w_kernel<<<(224 * 256 + 255) / 256, 256, 0, stream>>>(w1b, 198, 198, 224, 8, WP2);
    pad_w_kernel<<<(224 * 64 + 255) / 256, 256, 0, stream>>>(w2a, 198, 64, 224, 6, WP3);
    pad_w_kernel<<<(64 * 64 + 255) / 256, 256, 0, stream>>>(w2b, 64, 64, 64, 6, WP4);
    pad_w_kernel<<<(64 * 64 + 255) / 256, 256, 0, stream>>>(w3a, 64, 32, 64, 6, WP5);
    pad_w_kernel<<<(32 * 64 + 255) / 256, 256, 0, stream>>>(w3b, 32, 32, 32, 6, WP6);

    // ---- CSR build (shared by all 3 layers) ----
    hipMemsetAsync(deg, 0, NODES * sizeof(int), stream);
    hist_kernel<<<EB, 256, 0, stream>>>(dst, deg);
    scan_kernel<<<1, 1024, 0, stream>>>(deg, rowstart, cursor);
    scatter_kernel<<<EB, 256, 0, stream>>>(src, dst, cursor, csrc);

    // ---- layer 1 (114 -> 198 -> 198), ping-pong x,b0 -> b1 -> b0 ----
    csr_agg<114, false><<<AB, 256, 0, stream>>>(x, 114, rowstart, csrc, nullptr, nullptr, b0);
    gemm_kernel<114, 198, 32, true, false, false><<<GB32, 256, 0, stream>>>(
        x, 114, b0, WP1, b1a, nullptr, nullptr, b1, nullptr, nullptr);
    hipMemsetAsync(SUM, 0, 512 * sizeof(float), stream);
    gemm_kernel<198, 198, 32, false, true, false><<<GB32, 256, 0, stream>>>(
        b1, P, nullptr, WP2, b1b, nullptr, nullptr, b0, SUM, SQ);
    bn_finalize<198><<<1, 256, 0, stream>>>(SUM, SQ, g1, be1, SCALE, SHIFT);

    // ---- layer 2 (198 -> 64 -> 64); BN1 folded into agg + gemm stage ----
    csr_agg_v4<<<AB, 256, 0, stream>>>(b0, rowstart, csrc, SCALE, SHIFT, b1);
    gemm_kernel<198, 64, 32, true, false, true><<<GB32, 256, 0, stream>>>(
        b0, P, b1, WP3, b2a, SCALE, SHIFT, b1, nullptr, nullptr);
    hipMemsetAsync(SUM, 0, 512 * sizeof(float), stream);
    gemm_kernel<64, 64, 32, false, true, false><<<GB32, 256, 0, stream>>>(
        b1, P, nullptr, WP4, b2b, nullptr, nullptr, b0, SUM, SQ);
    bn_finalize<64><<<1, 256, 0, stream>>>(SUM, SQ, g2, be2, SCALE, SHIFT);

    // ---- layer 3 (64 -> 32 -> 32); BN2 folded ----
    csr_agg<64, true><<<AB, 256, 0, stream>>>(b0, P, rowstart, csrc, SCALE, SHIFT, b1);
    gemm_kernel<64, 32, 32, true, false, true><<<GB32, 256, 0, stream>>>(
        b0, P, b1, WP5, b3a, SCALE, SHIFT, b1, nullptr, nullptr);
    hipMemsetAsync(SUM, 0, 512 * sizeof(float), stream);
    gemm_kernel<32, 32, 32, false, true, false><<<GB32, 256, 0, stream>>>(
        b1, P, nullptr, WP6, b3b, nullptr, nullptr, b0, SUM, SQ);
    bn_finalize<32><<<1, 256, 0, stream>>>(SUM, SQ, g3, be3, SCALE, SHIFT);

    // ---- pool (BN3 folded) + head ----
    hipMemsetAsync(G, 0, GRAPHS * 32 * sizeof(float), stream);
    pool_kernel<<<(NODES * 32 + 255) / 256, 256, 0, stream>>>(b0, batch, SCALE, SHIFT, G);
    head_kernel<<<(GRAPHS + 255) / 256, 256, 0, stream>>>(G, fw1, fb1, fw2, fb2, ow, ob, out);
}

// Round 8
// 778.748 us; speedup vs baseline: 1.4164x; 1.3650x over previous
//
#include <hip/hip_runtime.h>

#define NODES  50000
#define EDGES  800000
#define GRAPHS 1024
#define P      200      // uniform row pitch (floats) for node-feature buffers

typedef __attribute__((ext_vector_type(8))) short short8v;  // 8 bf16 (4 VGPRs)
typedef __attribute__((ext_vector_type(4))) float f32x4;    // MFMA accumulator

__device__ __forceinline__ ushort f2bf(float f) {           // fp32 -> bf16 RNE
    uint u = __float_as_uint(f);
    u = u + 0x7FFFu + ((u >> 16) & 1u);
    return (ushort)(u >> 16);
}

// ---------------------------------------------------------------------------
// CSR build
// ---------------------------------------------------------------------------
__global__ void hist_kernel(const int* __restrict__ dst, int* __restrict__ deg) {
    int e = blockIdx.x * blockDim.x + threadIdx.x;
    if (e < EDGES) atomicAdd(&deg[dst[e]], 1);
}

__global__ void scan_kernel(const int* __restrict__ deg,
                            int* __restrict__ rowstart, int* __restrict__ cursor) {
    __shared__ int part[1024];
    int t = threadIdx.x;
    const int CH = (NODES + 1023) / 1024;   // 49
    int base = t * CH;
    int s = 0;
    for (int i = 0; i < CH; i++) {
        int n = base + i;
        if (n < NODES) s += deg[n];
    }
    part[t] = s;
    __syncthreads();
    for (int off = 1; off < 1024; off <<= 1) {
        int v = 0;
        if (t >= off) v = part[t - off];
        __syncthreads();
        if (t >= off) part[t] += v;
        __syncthreads();
    }
    int run = (t == 0) ? 0 : part[t - 1];
    for (int i = 0; i < CH; i++) {
        int n = base + i;
        if (n < NODES) {
            rowstart[n] = run;
            cursor[n]   = run;
            run += deg[n];
        }
    }
    if (t == 0) rowstart[NODES] = EDGES;
}

__global__ void scatter_kernel(const int* __restrict__ src, const int* __restrict__ dst,
                               int* __restrict__ cursor, int* __restrict__ csrc) {
    int e = blockIdx.x * blockDim.x + threadIdx.x;
    if (e < EDGES) {
        int p = atomicAdd(&cursor[dst[e]], 1);
        csrc[p] = src[e];
    }
}

// ---------------------------------------------------------------------------
// Weight -> MFMA-fragment-ordered bf16 hi/lo: out[h][c][ct][kg][col][j]
// (h: hi/lo, c: K-chunk of 32, ct: 16-col tile, kg: k-subgroup of 8, col: 0..15,
//  j: 0..7).  k = c*32+kg*8+j, n = ct*16+col; zero outside K x N.
// ---------------------------------------------------------------------------
__global__ void pad_w_mfma(const float* __restrict__ W, int K, int N, int NCH, int CT,
                           ushort* __restrict__ out) {
    int s = blockIdx.x * blockDim.x + threadIdx.x;
    int half = NCH * CT * 512;
    if (s >= 2 * half) return;
    int h = s / half;
    int r = s % half;
    int j = r & 7, col = (r >> 3) & 15, kg = (r >> 7) & 3;
    int rest = r >> 9;                  // c*CT + ct
    int ct = rest % CT, c = rest / CT;
    int k = c * 32 + kg * 8 + j;
    int n = ct * 16 + col;
    float v = (k < K && n < N) ? W[k * N + n] : 0.0f;
    ushort hi = f2bf(v);
    if (h == 0) out[s] = hi;
    else {
        float hf = __uint_as_float(((uint)hi) << 16);
        out[s] = f2bf(v - hf);
    }
}

// ---------------------------------------------------------------------------
// Aggregation, scalar path (D=114 packed input, D=64). Optional BN affine
// folded in: accumulates v*scale[c]+shift[c] == sum of BN(h_j).
// ---------------------------------------------------------------------------
template<int D, bool AFFINE>
__global__ void csr_agg(const float* __restrict__ feat, int fpitch,
                        const int* __restrict__ rowstart, const int* __restrict__ csrc,
                        const float* __restrict__ scale, const float* __restrict__ shift,
                        float* __restrict__ agg) {
    int wid  = (blockIdx.x * blockDim.x + threadIdx.x) >> 6;
    int lane = threadIdx.x & 63;
    if (wid >= NODES) return;
    constexpr int NI = (D + 63) / 64;
    float s[NI];
    float sc[NI], sh[NI];
#pragma unroll
    for (int i = 0; i < NI; i++) {
        s[i] = 0.0f;
        int c = lane + 64 * i;
        if (AFFINE && c < D) { sc[i] = scale[c]; sh[i] = shift[c]; }
    }
    int r0 = rowstart[wid], r1 = rowstart[wid + 1];
    for (int r = r0; r < r1; r++) {
        int sn = csrc[r];
        const float* fp = feat + (size_t)sn * fpitch;
#pragma unroll
        for (int i = 0; i < NI; i++) {
            int c = lane + 64 * i;
            if (c < D) {
                float v = fp[c];
                s[i] += AFFINE ? fmaf(v, sc[i], sh[i]) : v;
            }
        }
    }
    float* ap = agg + (size_t)wid * P;
#pragma unroll
    for (int i = 0; i < NI; i++) {
        int c = lane + 64 * i;
        if (c < D) ap[c] = s[i];
    }
}

// Vectorized aggregation for P-pitched features (row as 50 float4, lanes 0..49)
// with BN affine folded. Pad cols carry garbage (finite), never consumed.
__global__ void csr_agg_v4(const float* __restrict__ feat,
                           const int* __restrict__ rowstart, const int* __restrict__ csrc,
                           const float* __restrict__ scale, const float* __restrict__ shift,
                           float* __restrict__ agg) {
    int wid  = (blockIdx.x * blockDim.x + threadIdx.x) >> 6;
    int lane = threadIdx.x & 63;
    if (wid >= NODES) return;
    const float4* f4 = (const float4*)feat;
    float4 s = make_float4(0.f, 0.f, 0.f, 0.f);
    float4 sc = make_float4(0.f, 0.f, 0.f, 0.f), sh = sc;
    if (lane < 50) {
        sc = ((const float4*)scale)[lane];
        sh = ((const float4*)shift)[lane];
    }
    int r0 = rowstart[wid], r1 = rowstart[wid + 1];
    for (int r = r0; r < r1; r++) {
        int sn = csrc[r];
        if (lane < 50) {
            float4 v = f4[(size_t)sn * 50 + lane];
            s.x = fmaf(v.x, sc.x, s.x + sh.x);
            s.y = fmaf(v.y, sc.y, s.y + sh.y);
            s.z = fmaf(v.z, sc.z, s.z + sh.z);
            s.w = fmaf(v.w, sc.w, s.w + sh.w);
        }
    }
    if (lane < 50) ((float4*)agg)[(size_t)wid * 50 + lane] = s;
}

// ---------------------------------------------------------------------------
// MFMA GEMM with bf16 hi/lo split (fp32-grade accuracy, matrix pipe):
// OUT[m][n] = relu( (BN?(X[m]) + A2[m]) @ W + B ), optional BN-stat epilogue.
// Block = 64 rows x NP cols, 4 waves; wave w owns col-tiles [w*CTW, (w+1)*CTW).
// Per K-chunk(32): stage A 64x32 fp32 -> hi/lo bf16 fragments in LDS (16KB);
// W fragments read directly from pre-converted global (L2-resident);
// 3 MFMA per tile pair: Ahi*Whi + Alo*Whi + Ahi*Wlo  (lo*lo ~2^-16, dropped).
// In-place OUT==A2 safe: block reads only its own rows, all before epilogue.
// ---------------------------------------------------------------------------
template<int K, int N, bool ADD2, bool STATS, bool BNX>
__launch_bounds__(256)
__global__ void gemm_mfma(const float* __restrict__ X, int xpitch,
                          const float* __restrict__ A2,
                          const ushort* __restrict__ WF,  // [2][NCH][CT][4][16][8] bf16
                          const float* __restrict__ B,
                          const float* __restrict__ scale, const float* __restrict__ shift,
                          float* __restrict__ OUT,
                          float* __restrict__ gsum, float* __restrict__ gsq) {
    constexpr int KP  = ((K + 31) / 32) * 32;
    constexpr int NCH = KP / 32;
    constexpr int NP  = ((N + 63) / 64) * 64;   // 64 or 256
    constexpr int CT  = NP / 16;
    constexpr int CTW = CT / 4;                 // col-tiles per wave
    static_assert(CT % 4 == 0, "col tiles must split across 4 waves");

    __shared__ __align__(16) ushort A_lds[2][4][4][16][8]; // [h][rt][kg][row][j]
    __shared__ float shSum[STATS ? NP : 4];
    __shared__ float shSq [STATS ? NP : 4];

    const int tid  = threadIdx.x;
    const int lane = tid & 63;
    const int wv   = tid >> 6;
    const int node0 = blockIdx.x * 64;

    if (STATS) {
        for (int n = tid; n < NP; n += 256) { shSum[n] = 0.0f; shSq[n] = 0.0f; }
    }

    f32x4 acc[4][CTW] = {};

    const int sr  = tid >> 2;   // staging row 0..63
    const int skg = tid & 3;    // staging k-group (8 k's)
    const size_t fstride = (size_t)NCH * CT * 512;   // shorts per hi/lo half

    for (int c = 0; c < NCH; c++) {
        const int kbase = c * 32;
        // ---- stage + convert A chunk (64 x 32) ----
        {
            const int gn = node0 + sr;
            const int k0 = kbase + skg * 8;
            float v[8];
#pragma unroll
            for (int j = 0; j < 8; j++) {
                int gk = k0 + j;
                float t = 0.0f;
                if (gn < NODES && gk < K) {
                    t = X[(size_t)gn * xpitch + gk];
                    if (BNX) t = fmaf(t, scale[gk], shift[gk]);
                    if (ADD2) t += A2[(size_t)gn * P + gk];
                }
                v[j] = t;
            }
            short8v hv, lv;
#pragma unroll
            for (int j = 0; j < 8; j++) {
                ushort h = f2bf(v[j]);
                float hf = __uint_as_float(((uint)h) << 16);
                ushort l = f2bf(v[j] - hf);
                hv[j] = (short)h; lv[j] = (short)l;
            }
            *(short8v*)&A_lds[0][sr >> 4][skg][sr & 15][0] = hv;
            *(short8v*)&A_lds[1][sr >> 4][skg][sr & 15][0] = lv;
        }
        __syncthreads();

        // ---- fragments + MFMA ----
        const int kg = lane >> 4, rw = lane & 15;
        short8v ah[4], al[4];
#pragma unroll
        for (int rt = 0; rt < 4; rt++) {
            ah[rt] = *(const short8v*)&A_lds[0][rt][kg][rw][0];
            al[rt] = *(const short8v*)&A_lds[1][rt][kg][rw][0];
        }
#pragma unroll
        for (int t = 0; t < CTW; t++) {
            const int ct = wv * CTW + t;
            const size_t fb = ((size_t)(c * CT + ct)) * 512 + (size_t)lane * 8;
            short8v wh = *(const short8v*)(WF + fb);
            short8v wl = *(const short8v*)(WF + fstride + fb);
#pragma unroll
            for (int rt = 0; rt < 4; rt++) {
                acc[rt][t] = __builtin_amdgcn_mfma_f32_16x16x32_bf16(ah[rt], wh, acc[rt][t], 0, 0, 0);
                acc[rt][t] = __builtin_amdgcn_mfma_f32_16x16x32_bf16(al[rt], wh, acc[rt][t], 0, 0, 0);
                acc[rt][t] = __builtin_amdgcn_mfma_f32_16x16x32_bf16(ah[rt], wl, acc[rt][t], 0, 0, 0);
            }
        }
        __syncthreads();
    }

    // ---- epilogue: bias, relu, store, stats ----
    // D layout (verified): lane holds D[row=(lane>>4)*4+j][col=lane&15] per tile
    const int mg = lane >> 4, colb = lane & 15;
#pragma unroll
    for (int t = 0; t < CTW; t++) {
        const int ct = wv * CTW + t;
        const int n = ct * 16 + colb;
        const float bn = (n < N) ? B[n] : 0.0f;
        float psum = 0.0f, psq = 0.0f;
#pragma unroll
        for (int rt = 0; rt < 4; rt++) {
#pragma unroll
            for (int j = 0; j < 4; j++) {
                int m = node0 + rt * 16 + mg * 4 + j;
                float vv = fmaxf(acc[rt][t][j] + bn, 0.0f);
                if (m < NODES && n < N) {
                    OUT[(size_t)m * P + n] = vv;
                    if (STATS) { psum += vv; psq += vv * vv; }
                }
            }
        }
        if (STATS && n < N) {
            atomicAdd(&shSum[n], psum);
            atomicAdd(&shSq[n], psq);
        }
    }
    if (STATS) {
        __syncthreads();
        for (int n = tid; n < N; n += 256) {
            atomicAdd(&gsum[n], shSum[n]);
            atomicAdd(&gsq[n], shSq[n]);
        }
    }
}

// ---------------------------------------------------------------------------
// BN finalize (scale/shift for folded apply)
// ---------------------------------------------------------------------------
template<int N>
__global__ void bn_finalize(const float* __restrict__ sum, const float* __restrict__ sq,
                            const float* __restrict__ gamma, const float* __restrict__ beta,
                            float* __restrict__ scale, float* __restrict__ shift) {
    int n = threadIdx.x;
    if (n < N) {
        float mean = sum[n] * (1.0f / NODES);
        float var  = sq[n] * (1.0f / NODES) - mean * mean;
        var = var < 0.0f ? 0.0f : var;
        float sc = gamma[n] * rsqrtf(var + 1e-5f);
        scale[n] = sc;
        shift[n] = beta[n] - mean * sc;
    }
}

// ---------------------------------------------------------------------------
// Pool (BN3 affine folded) + head MLP
// ---------------------------------------------------------------------------
__global__ void pool_kernel(const float* __restrict__ h, const int* __restrict__ batch,
                            const float* __restrict__ scale, const float* __restrict__ shift,
                            float* __restrict__ g) {
    int idx = blockIdx.x * blockDim.x + threadIdx.x;
    if (idx >= NODES * 32) return;
    int n = idx >> 5, f = idx & 31;
    float v = fmaf(h[(size_t)n * P + f], scale[f], shift[f]);
    atomicAdd(&g[batch[n] * 32 + f], v);
}

__global__ void head_kernel(const float* __restrict__ g,
                            const float* __restrict__ fw1, const float* __restrict__ fb1,
                            const float* __restrict__ fw2, const float* __restrict__ fb2,
                            const float* __restrict__ ow, const float* __restrict__ ob,
                            float* __restrict__ out) {
    int gi = blockIdx.x * blockDim.x + threadIdx.x;
    if (gi >= GRAPHS) return;
    float v[32];
#pragma unroll
    for (int k = 0; k < 32; k++) v[k] = g[gi * 32 + k];
    float a1[16];
#pragma unroll
    for (int o = 0; o < 16; o++) {
        float s = fb1[o];
#pragma unroll
        for (int k = 0; k < 32; k++) s = fmaf(v[k], fw1[k * 16 + o], s);
        a1[o] = s > 0.0f ? s : 0.0f;
    }
    float a2[8];
#pragma unroll
    for (int o = 0; o < 8; o++) {
        float s = fb2[o];
#pragma unroll
        for (int k = 0; k < 16; k++) s = fmaf(a1[k], fw2[k * 8 + o], s);
        a2[o] = s > 0.0f ? s : 0.0f;
    }
#pragma unroll
    for (int o = 0; o < 2; o++) {
        float s = ob[o];
#pragma unroll
        for (int k = 0; k < 8; k++) s = fmaf(a2[k], ow[k * 2 + o], s);
        out[gi * 2 + o] = s;
    }
}

// ---------------------------------------------------------------------------
extern "C" void kernel_launch(void* const* d_in, const int* in_sizes, int n_in,
                              void* d_out, int out_size, void* d_ws, size_t ws_size,
                              hipStream_t stream) {
    const float* x     = (const float*)d_in[0];
    const int*   ei    = (const int*)d_in[1];
    const int*   batch = (const int*)d_in[2];
    const float *w1a = (const float*)d_in[3],  *b1a = (const float*)d_in[4];
    const float *w1b = (const float*)d_in[5],  *b1b = (const float*)d_in[6];
    const float *g1  = (const float*)d_in[7],  *be1 = (const float*)d_in[8];
    const float *w2a = (const float*)d_in[9],  *b2a = (const float*)d_in[10];
    const float *w2b = (const float*)d_in[11], *b2b = (const float*)d_in[12];
    const float *g2  = (const float*)d_in[13], *be2 = (const float*)d_in[14];
    const float *w3a = (const float*)d_in[15], *b3a = (const float*)d_in[16];
    const float *w3b = (const float*)d_in[17], *b3b = (const float*)d_in[18];
    const float *g3  = (const float*)d_in[19], *be3 = (const float*)d_in[20];
    const float *fw1 = (const float*)d_in[21], *fb1 = (const float*)d_in[22];
    const float *fw2 = (const float*)d_in[23], *fb2 = (const float*)d_in[24];
    const float *ow  = (const float*)d_in[25], *ob  = (const float*)d_in[26];
    const int* src = ei;
    const int* dst = ei + EDGES;

    float* ws    = (float*)d_ws;
    float* b0    = ws;                                  // 50000 x 200
    float* b1    = ws + (size_t)NODES * P;              // 50000 x 200
    float* SUM   = ws + (size_t)2 * NODES * P;          // 256
    float* SQ    = SUM + 256;
    float* SCALE = SUM + 512;
    float* SHIFT = SUM + 768;
    float* G     = SUM + 1024;                          // 1024 x 32
    int*   deg      = (int*)(G + GRAPHS * 32);          // 50000
    int*   rowstart = deg + NODES;                      // 50001
    int*   cursor   = rowstart + NODES + 1;             // 50000
    int*   csrc     = cursor + NODES;                   // 800000
    uintptr_t wfp = ((uintptr_t)(csrc + EDGES) + 15) & ~(uintptr_t)15;
    ushort* WF1 = (ushort*)wfp;                         // 2*4*16*512  = 65536
    ushort* WF2 = WF1 + 65536;                          // 2*7*16*512  = 114688
    ushort* WF3 = WF2 + 114688;                         // 2*7*4*512   = 28672
    ushort* WF4 = WF3 + 28672;                          // 2*2*4*512   = 8192
    ushort* WF5 = WF4 + 8192;                           // 2*2*4*512   = 8192
    ushort* WF6 = WF5 + 8192;                           // 2*1*4*512   = 4096
    float* out = (float*)d_out;

    const int GB64 = (NODES + 63) / 64;      // 782 gemm blocks
    const int AB = (NODES * 64 + 255) / 256; // agg blocks (wave per node)
    const int EB = (EDGES + 255) / 256;

    // ---- weight conversion to MFMA fragment layout (once per launch) ----
    pad_w_mfma<<<(65536 + 255) / 256, 256, 0, stream>>>(w1a, 114, 198, 4, 16, WF1);
    pad_w_mfma<<<(114688 + 255) / 256, 256, 0, stream>>>(w1b, 198, 198, 7, 16, WF2);
    pad_w_mfma<<<(28672 + 255) / 256, 256, 0, stream>>>(w2a, 198, 64, 7, 4, WF3);
    pad_w_mfma<<<(8192 + 255) / 256, 256, 0, stream>>>(w2b, 64, 64, 2, 4, WF4);
    pad_w_mfma<<<(8192 + 255) / 256, 256, 0, stream>>>(w3a, 64, 32, 2, 4, WF5);
    pad_w_mfma<<<(4096 + 255) / 256, 256, 0, stream>>>(w3b, 32, 32, 1, 4, WF6);

    // ---- CSR build (shared by all 3 layers) ----
    hipMemsetAsync(deg, 0, NODES * sizeof(int), stream);
    hist_kernel<<<EB, 256, 0, stream>>>(dst, deg);
    scan_kernel<<<1, 1024, 0, stream>>>(deg, rowstart, cursor);
    scatter_kernel<<<EB, 256, 0, stream>>>(src, dst, cursor, csrc);

    // ---- layer 1 (114 -> 198 -> 198), ping-pong x,b0 -> b1 -> b0 ----
    csr_agg<114, false><<<AB, 256, 0, stream>>>(x, 114, rowstart, csrc, nullptr, nullptr, b0);
    gemm_mfma<114, 198, true, false, false><<<GB64, 256, 0, stream>>>(
        x, 114, b0, WF1, b1a, nullptr, nullptr, b1, nullptr, nullptr);
    hipMemsetAsync(SUM, 0, 512 * sizeof(float), stream);
    gemm_mfma<198, 198, false, true, false><<<GB64, 256, 0, stream>>>(
        b1, P, nullptr, WF2, b1b, nullptr, nullptr, b0, SUM, SQ);
    bn_finalize<198><<<1, 256, 0, stream>>>(SUM, SQ, g1, be1, SCALE, SHIFT);

    // ---- layer 2 (198 -> 64 -> 64); BN1 folded into agg + gemm stage ----
    csr_agg_v4<<<AB, 256, 0, stream>>>(b0, rowstart, csrc, SCALE, SHIFT, b1);
    gemm_mfma<198, 64, true, false, true><<<GB64, 256, 0, stream>>>(
        b0, P, b1, WF3, b2a, SCALE, SHIFT, b1, nullptr, nullptr);
    hipMemsetAsync(SUM, 0, 512 * sizeof(float), stream);
    gemm_mfma<64, 64, false, true, false><<<GB64, 256, 0, stream>>>(
        b1, P, nullptr, WF4, b2b, nullptr, nullptr, b0, SUM, SQ);
    bn_finalize<64><<<1, 256, 0, stream>>>(SUM, SQ, g2, be2, SCALE, SHIFT);

    // ---- layer 3 (64 -> 32 -> 32); BN2 folded ----
    csr_agg<64, true><<<AB, 256, 0, stream>>>(b0, P, rowstart, csrc, SCALE, SHIFT, b1);
    gemm_mfma<64, 32, true, false, true><<<GB64, 256, 0, stream>>>(
        b0, P, b1, WF5, b3a, SCALE, SHIFT, b1, nullptr, nullptr);
    hipMemsetAsync(SUM, 0, 512 * sizeof(float), stream);
    gemm_mfma<32, 32, false, true, false><<<GB64, 256, 0, stream>>>(
        b1, P, nullptr, WF6, b3b, nullptr, nullptr, b0, SUM, SQ);
    bn_finalize<32><<<1, 256, 0, stream>>>(SUM, SQ, g3, be3, SCALE, SHIFT);

    // ---- pool (BN3 folded) + head ----
    hipMemsetAsync(G, 0, GRAPHS * 32 * sizeof(float), stream);
    pool_kernel<<<(NODES * 32 + 255) / 256, 256, 0, stream>>>(b0, batch, SCALE, SHIFT, G);
    head_kernel<<<(GRAPHS + 255) / 256, 256, 0, stream>>>(G, fw1, fb1, fw2, fb2, ow, ob, out);
}

// Round 9
// 674.871 us; speedup vs baseline: 1.6344x; 1.1539x over previous
//
#include <hip/hip_runtime.h>

#define NODES  50000
#define EDGES  800000
#define GRAPHS 1024
#define P      200      // uniform row pitch (floats) for node-feature buffers

#define SCAN_BLK 256
#define SCAN_NB  ((NODES + SCAN_BLK - 1) / SCAN_BLK)   // 196

typedef __attribute__((ext_vector_type(8))) short short8v;  // 8 bf16 (4 VGPRs)
typedef __attribute__((ext_vector_type(4))) float f32x4;    // MFMA accumulator

__device__ __forceinline__ ushort f2bf(float f) {           // fp32 -> bf16 RNE
    uint u = __float_as_uint(f);
    u = u + 0x7FFFu + ((u >> 16) & 1u);
    return (ushort)(u >> 16);
}

// ---------------------------------------------------------------------------
// CSR build
// ---------------------------------------------------------------------------
__global__ void hist_kernel(const int* __restrict__ dst, int* __restrict__ deg) {
    int e = blockIdx.x * blockDim.x + threadIdx.x;
    if (e < EDGES) atomicAdd(&deg[dst[e]], 1);
}

// 3-kernel device-wide exclusive scan of deg -> rowstart/cursor
__global__ void scan_part(const int* __restrict__ deg, int* __restrict__ part) {
    __shared__ int sh[SCAN_BLK];
    int t = threadIdx.x;
    int n = blockIdx.x * SCAN_BLK + t;
    sh[t] = (n < NODES) ? deg[n] : 0;
    __syncthreads();
    for (int off = SCAN_BLK / 2; off > 0; off >>= 1) {
        if (t < off) sh[t] += sh[t + off];
        __syncthreads();
    }
    if (t == 0) part[blockIdx.x] = sh[0];
}

__global__ void scan_scan(int* __restrict__ part) {
    __shared__ int sh[SCAN_BLK];
    int t = threadIdx.x;
    int v = (t < SCAN_NB) ? part[t] : 0;
    sh[t] = v;
    __syncthreads();
    for (int off = 1; off < SCAN_BLK; off <<= 1) {
        int u = 0;
        if (t >= off) u = sh[t - off];
        __syncthreads();
        if (t >= off) sh[t] += u;
        __syncthreads();
    }
    if (t < SCAN_NB) part[t] = sh[t] - v;   // exclusive
}

__global__ void scan_expand(const int* __restrict__ deg, const int* __restrict__ part,
                            int* __restrict__ rowstart, int* __restrict__ cursor) {
    __shared__ int sh[SCAN_BLK];
    int t = threadIdx.x;
    int n = blockIdx.x * SCAN_BLK + t;
    int v = (n < NODES) ? deg[n] : 0;
    sh[t] = v;
    __syncthreads();
    for (int off = 1; off < SCAN_BLK; off <<= 1) {
        int u = 0;
        if (t >= off) u = sh[t - off];
        __syncthreads();
        if (t >= off) sh[t] += u;
        __syncthreads();
    }
    int excl = sh[t] - v + part[blockIdx.x];
    if (n < NODES) {
        rowstart[n] = excl;
        cursor[n]   = excl;
        if (n == NODES - 1) rowstart[NODES] = excl + v;
    }
}

__global__ void scatter_kernel(const int* __restrict__ src, const int* __restrict__ dst,
                               int* __restrict__ cursor, int* __restrict__ csrc) {
    int e = blockIdx.x * blockDim.x + threadIdx.x;
    if (e < EDGES) {
        int p = atomicAdd(&cursor[dst[e]], 1);
        csrc[p] = src[e];
    }
}

// ---------------------------------------------------------------------------
// Weight -> MFMA-fragment-ordered bf16 hi/lo: out[h][c][ct][kg][col][j]
// (h: hi/lo, c: K-chunk of 32, ct: 16-col tile, kg: k-subgroup of 8, col: 0..15,
//  j: 0..7).  k = c*32+kg*8+j, n = ct*16+col; zero outside K x N.
// ---------------------------------------------------------------------------
__global__ void pad_w_mfma(const float* __restrict__ W, int K, int N, int NCH, int CT,
                           ushort* __restrict__ out) {
    int s = blockIdx.x * blockDim.x + threadIdx.x;
    int half = NCH * CT * 512;
    if (s >= 2 * half) return;
    int h = s / half;
    int r = s % half;
    int j = r & 7, col = (r >> 3) & 15, kg = (r >> 7) & 3;
    int rest = r >> 9;                  // c*CT + ct
    int ct = rest % CT, c = rest / CT;
    int k = c * 32 + kg * 8 + j;
    int n = ct * 16 + col;
    float v = (k < K && n < N) ? W[k * N + n] : 0.0f;
    ushort hi = f2bf(v);
    if (h == 0) out[s] = hi;
    else {
        float hf = __uint_as_float(((uint)hi) << 16);
        out[s] = f2bf(v - hf);
    }
}

// ---------------------------------------------------------------------------
// Aggregation, scalar path (D=114 packed input, D=64). Optional BN affine
// folded in: accumulates v*scale[c]+shift[c] == sum of BN(h_j).
// ---------------------------------------------------------------------------
template<int D, bool AFFINE>
__global__ void csr_agg(const float* __restrict__ feat, int fpitch,
                        const int* __restrict__ rowstart, const int* __restrict__ csrc,
                        const float* __restrict__ scale, const float* __restrict__ shift,
                        float* __restrict__ agg) {
    int wid  = (blockIdx.x * blockDim.x + threadIdx.x) >> 6;
    int lane = threadIdx.x & 63;
    if (wid >= NODES) return;
    constexpr int NI = (D + 63) / 64;
    float s[NI];
    float sc[NI], sh[NI];
#pragma unroll
    for (int i = 0; i < NI; i++) {
        s[i] = 0.0f;
        int c = lane + 64 * i;
        if (AFFINE && c < D) { sc[i] = scale[c]; sh[i] = shift[c]; }
    }
    int r0 = rowstart[wid], r1 = rowstart[wid + 1];
    for (int r = r0; r < r1; r++) {
        int sn = csrc[r];
        const float* fp = feat + (size_t)sn * fpitch;
#pragma unroll
        for (int i = 0; i < NI; i++) {
            int c = lane + 64 * i;
            if (c < D) {
                float v = fp[c];
                s[i] += AFFINE ? fmaf(v, sc[i], sh[i]) : v;
            }
        }
    }
    float* ap = agg + (size_t)wid * P;
#pragma unroll
    for (int i = 0; i < NI; i++) {
        int c = lane + 64 * i;
        if (c < D) ap[c] = s[i];
    }
}

// Vectorized aggregation for P-pitched features (row as 50 float4, lanes 0..49)
// with BN affine folded. Pad cols carry garbage (finite), never consumed.
__global__ void csr_agg_v4(const float* __restrict__ feat,
                           const int* __restrict__ rowstart, const int* __restrict__ csrc,
                           const float* __restrict__ scale, const float* __restrict__ shift,
                           float* __restrict__ agg) {
    int wid  = (blockIdx.x * blockDim.x + threadIdx.x) >> 6;
    int lane = threadIdx.x & 63;
    if (wid >= NODES) return;
    const float4* f4 = (const float4*)feat;
    float4 s = make_float4(0.f, 0.f, 0.f, 0.f);
    float4 sc = make_float4(0.f, 0.f, 0.f, 0.f), sh = sc;
    if (lane < 50) {
        sc = ((const float4*)scale)[lane];
        sh = ((const float4*)shift)[lane];
    }
    int r0 = rowstart[wid], r1 = rowstart[wid + 1];
    for (int r = r0; r < r1; r++) {
        int sn = csrc[r];
        if (lane < 50) {
            float4 v = f4[(size_t)sn * 50 + lane];
            s.x = fmaf(v.x, sc.x, s.x + sh.x);
            s.y = fmaf(v.y, sc.y, s.y + sh.y);
            s.z = fmaf(v.z, sc.z, s.z + sh.z);
            s.w = fmaf(v.w, sc.w, s.w + sh.w);
        }
    }
    if (lane < 50) ((float4*)agg)[(size_t)wid * 50 + lane] = s;
}

// ---------------------------------------------------------------------------
// MFMA GEMM with bf16 hi/lo split (fp32-grade accuracy, matrix pipe):
// OUT[m][n] = relu( (BN?(X[m]) + A2[m]) @ W + B ), optional BN-stat epilogue.
// Block = 64 rows x NP cols, 4 waves; wave w owns col-tiles [w*CTW, (w+1)*CTW).
// Per K-chunk(32): stage A 64x32 fp32 -> hi/lo bf16 fragments in LDS (16KB);
// W fragments read directly from pre-converted global (L2-resident);
// 3 MFMA per tile pair: Ahi*Whi + Alo*Whi + Ahi*Wlo  (lo*lo ~2^-16, dropped).
// In-place OUT==A2 safe: block reads only its own rows, all before epilogue.
// ---------------------------------------------------------------------------
template<int K, int N, bool ADD2, bool STATS, bool BNX>
__launch_bounds__(256)
__global__ void gemm_mfma(const float* __restrict__ X, int xpitch,
                          const float* __restrict__ A2,
                          const ushort* __restrict__ WF,  // [2][NCH][CT][4][16][8] bf16
                          const float* __restrict__ B,
                          const float* __restrict__ scale, const float* __restrict__ shift,
                          float* __restrict__ OUT,
                          float* __restrict__ gsum, float* __restrict__ gsq) {
    constexpr int KP  = ((K + 31) / 32) * 32;
    constexpr int NCH = KP / 32;
    constexpr int NP  = ((N + 63) / 64) * 64;   // 64 or 256
    constexpr int CT  = NP / 16;
    constexpr int CTW = CT / 4;                 // col-tiles per wave
    static_assert(CT % 4 == 0, "col tiles must split across 4 waves");

    __shared__ __align__(16) ushort A_lds[2][4][4][16][8]; // [h][rt][kg][row][j]
    __shared__ float shSum[STATS ? NP : 4];
    __shared__ float shSq [STATS ? NP : 4];

    const int tid  = threadIdx.x;
    const int lane = tid & 63;
    const int wv   = tid >> 6;
    const int node0 = blockIdx.x * 64;

    if (STATS) {
        for (int n = tid; n < NP; n += 256) { shSum[n] = 0.0f; shSq[n] = 0.0f; }
    }

    f32x4 acc[4][CTW] = {};

    const int sr  = tid >> 2;   // staging row 0..63
    const int skg = tid & 3;    // staging k-group (8 k's)
    const size_t fstride = (size_t)NCH * CT * 512;   // shorts per hi/lo half

    for (int c = 0; c < NCH; c++) {
        const int kbase = c * 32;
        // ---- stage + convert A chunk (64 x 32) ----
        {
            const int gn = node0 + sr;
            const int k0 = kbase + skg * 8;
            float v[8];
#pragma unroll
            for (int j = 0; j < 8; j++) {
                int gk = k0 + j;
                float t = 0.0f;
                if (gn < NODES && gk < K) {
                    t = X[(size_t)gn * xpitch + gk];
                    if (BNX) t = fmaf(t, scale[gk], shift[gk]);
                    if (ADD2) t += A2[(size_t)gn * P + gk];
                }
                v[j] = t;
            }
            short8v hv, lv;
#pragma unroll
            for (int j = 0; j < 8; j++) {
                ushort h = f2bf(v[j]);
                float hf = __uint_as_float(((uint)h) << 16);
                ushort l = f2bf(v[j] - hf);
                hv[j] = (short)h; lv[j] = (short)l;
            }
            *(short8v*)&A_lds[0][sr >> 4][skg][sr & 15][0] = hv;
            *(short8v*)&A_lds[1][sr >> 4][skg][sr & 15][0] = lv;
        }
        __syncthreads();

        // ---- fragments + MFMA ----
        const int kg = lane >> 4, rw = lane & 15;
        short8v ah[4], al[4];
#pragma unroll
        for (int rt = 0; rt < 4; rt++) {
            ah[rt] = *(const short8v*)&A_lds[0][rt][kg][rw][0];
            al[rt] = *(const short8v*)&A_lds[1][rt][kg][rw][0];
        }
#pragma unroll
        for (int t = 0; t < CTW; t++) {
            const int ct = wv * CTW + t;
            const size_t fb = ((size_t)(c * CT + ct)) * 512 + (size_t)lane * 8;
            short8v wh = *(const short8v*)(WF + fb);
            short8v wl = *(const short8v*)(WF + fstride + fb);
#pragma unroll
            for (int rt = 0; rt < 4; rt++) {
                acc[rt][t] = __builtin_amdgcn_mfma_f32_16x16x32_bf16(ah[rt], wh, acc[rt][t], 0, 0, 0);
                acc[rt][t] = __builtin_amdgcn_mfma_f32_16x16x32_bf16(al[rt], wh, acc[rt][t], 0, 0, 0);
                acc[rt][t] = __builtin_amdgcn_mfma_f32_16x16x32_bf16(ah[rt], wl, acc[rt][t], 0, 0, 0);
            }
        }
        __syncthreads();
    }

    // ---- epilogue: bias, relu, store, stats ----
    // D layout (verified): lane holds D[row=(lane>>4)*4+j][col=lane&15] per tile
    const int mg = lane >> 4, colb = lane & 15;
#pragma unroll
    for (int t = 0; t < CTW; t++) {
        const int ct = wv * CTW + t;
        const int n = ct * 16 + colb;
        const float bn = (n < N) ? B[n] : 0.0f;
        float psum = 0.0f, psq = 0.0f;
#pragma unroll
        for (int rt = 0; rt < 4; rt++) {
#pragma unroll
            for (int j = 0; j < 4; j++) {
                int m = node0 + rt * 16 + mg * 4 + j;
                float vv = fmaxf(acc[rt][t][j] + bn, 0.0f);
                if (m < NODES && n < N) {
                    OUT[(size_t)m * P + n] = vv;
                    if (STATS) { psum += vv; psq += vv * vv; }
                }
            }
        }
        if (STATS && n < N) {
            atomicAdd(&shSum[n], psum);
            atomicAdd(&shSq[n], psq);
        }
    }
    if (STATS) {
        __syncthreads();
        for (int n = tid; n < N; n += 256) {
            atomicAdd(&gsum[n], shSum[n]);
            atomicAdd(&gsq[n], shSq[n]);
        }
    }
}

// ---------------------------------------------------------------------------
// BN finalize (scale/shift for folded apply)
// ---------------------------------------------------------------------------
template<int N>
__global__ void bn_finalize(const float* __restrict__ sum, const float* __restrict__ sq,
                            const float* __restrict__ gamma, const float* __restrict__ beta,
                            float* __restrict__ scale, float* __restrict__ shift) {
    int n = threadIdx.x;
    if (n < N) {
        float mean = sum[n] * (1.0f / NODES);
        float var  = sq[n] * (1.0f / NODES) - mean * mean;
        var = var < 0.0f ? 0.0f : var;
        float sc = gamma[n] * rsqrtf(var + 1e-5f);
        scale[n] = sc;
        shift[n] = beta[n] - mean * sc;
    }
}

// ---------------------------------------------------------------------------
// Pool (BN3 affine folded) + head MLP
// ---------------------------------------------------------------------------
__global__ void pool_kernel(const float* __restrict__ h, const int* __restrict__ batch,
                            const float* __restrict__ scale, const float* __restrict__ shift,
                            float* __restrict__ g) {
    int idx = blockIdx.x * blockDim.x + threadIdx.x;
    if (idx >= NODES * 32) return;
    int n = idx >> 5, f = idx & 31;
    float v = fmaf(h[(size_t)n * P + f], scale[f], shift[f]);
    atomicAdd(&g[batch[n] * 32 + f], v);
}

__global__ void head_kernel(const float* __restrict__ g,
                            const float* __restrict__ fw1, const float* __restrict__ fb1,
                            const float* __restrict__ fw2, const float* __restrict__ fb2,
                            const float* __restrict__ ow, const float* __restrict__ ob,
                            float* __restrict__ out) {
    int gi = blockIdx.x * blockDim.x + threadIdx.x;
    if (gi >= GRAPHS) return;
    float v[32];
#pragma unroll
    for (int k = 0; k < 32; k++) v[k] = g[gi * 32 + k];
    float a1[16];
#pragma unroll
    for (int o = 0; o < 16; o++) {
        float s = fb1[o];
#pragma unroll
        for (int k = 0; k < 32; k++) s = fmaf(v[k], fw1[k * 16 + o], s);
        a1[o] = s > 0.0f ? s : 0.0f;
    }
    float a2[8];
#pragma unroll
    for (int o = 0; o < 8; o++) {
        float s = fb2[o];
#pragma unroll
        for (int k = 0; k < 16; k++) s = fmaf(a1[k], fw2[k * 8 + o], s);
        a2[o] = s > 0.0f ? s : 0.0f;
    }
#pragma unroll
    for (int o = 0; o < 2; o++) {
        float s = ob[o];
#pragma unroll
        for (int k = 0; k < 8; k++) s = fmaf(a2[k], ow[k * 2 + o], s);
        out[gi * 2 + o] = s;
    }
}

// ---------------------------------------------------------------------------
extern "C" void kernel_launch(void* const* d_in, const int* in_sizes, int n_in,
                              void* d_out, int out_size, void* d_ws, size_t ws_size,
                              hipStream_t stream) {
    const float* x     = (const float*)d_in[0];
    const int*   ei    = (const int*)d_in[1];
    const int*   batch = (const int*)d_in[2];
    const float *w1a = (const float*)d_in[3],  *b1a = (const float*)d_in[4];
    const float *w1b = (const float*)d_in[5],  *b1b = (const float*)d_in[6];
    const float *g1  = (const float*)d_in[7],  *be1 = (const float*)d_in[8];
    const float *w2a = (const float*)d_in[9],  *b2a = (const float*)d_in[10];
    const float *w2b = (const float*)d_in[11], *b2b = (const float*)d_in[12];
    const float *g2  = (const float*)d_in[13], *be2 = (const float*)d_in[14];
    const float *w3a = (const float*)d_in[15], *b3a = (const float*)d_in[16];
    const float *w3b = (const float*)d_in[17], *b3b = (const float*)d_in[18];
    const float *g3  = (const float*)d_in[19], *be3 = (const float*)d_in[20];
    const float *fw1 = (const float*)d_in[21], *fb1 = (const float*)d_in[22];
    const float *fw2 = (const float*)d_in[23], *fb2 = (const float*)d_in[24];
    const float *ow  = (const float*)d_in[25], *ob  = (const float*)d_in[26];
    const int* src = ei;
    const int* dst = ei + EDGES;

    float* ws    = (float*)d_ws;
    float* b0    = ws;                                  // 50000 x 200
    float* b1    = ws + (size_t)NODES * P;              // 50000 x 200
    float* SUM   = ws + (size_t)2 * NODES * P;          // 256
    float* SQ    = SUM + 256;
    float* SCALE = SUM + 512;
    float* SHIFT = SUM + 768;
    float* G     = SUM + 1024;                          // 1024 x 32
    int*   deg      = (int*)(G + GRAPHS * 32);          // 50000
    int*   rowstart = deg + NODES;                      // 50001
    int*   cursor   = rowstart + NODES + 1;             // 50000
    int*   part     = cursor + NODES;                   // 256 (scan partials)
    int*   csrc     = part + 256;                       // 800000
    uintptr_t wfp = ((uintptr_t)(csrc + EDGES) + 15) & ~(uintptr_t)15;
    ushort* WF1 = (ushort*)wfp;                         // 2*4*16*512  = 65536
    ushort* WF2 = WF1 + 65536;                          // 2*7*16*512  = 114688
    ushort* WF3 = WF2 + 114688;                         // 2*7*4*512   = 28672
    ushort* WF4 = WF3 + 28672;                          // 2*2*4*512   = 8192
    ushort* WF5 = WF4 + 8192;                           // 2*2*4*512   = 8192
    ushort* WF6 = WF5 + 8192;                           // 2*1*4*512   = 4096
    float* out = (float*)d_out;

    const int GB64 = (NODES + 63) / 64;      // 782 gemm blocks
    const int AB = (NODES * 64 + 255) / 256; // agg blocks (wave per node)
    const int EB = (EDGES + 255) / 256;

    // ---- weight conversion to MFMA fragment layout (once per launch) ----
    pad_w_mfma<<<(65536 + 255) / 256, 256, 0, stream>>>(w1a, 114, 198, 4, 16, WF1);
    pad_w_mfma<<<(114688 + 255) / 256, 256, 0, stream>>>(w1b, 198, 198, 7, 16, WF2);
    pad_w_mfma<<<(28672 + 255) / 256, 256, 0, stream>>>(w2a, 198, 64, 7, 4, WF3);
    pad_w_mfma<<<(8192 + 255) / 256, 256, 0, stream>>>(w2b, 64, 64, 2, 4, WF4);
    pad_w_mfma<<<(8192 + 255) / 256, 256, 0, stream>>>(w3a, 64, 32, 2, 4, WF5);
    pad_w_mfma<<<(4096 + 255) / 256, 256, 0, stream>>>(w3b, 32, 32, 1, 4, WF6);

    // ---- CSR build (shared by all 3 layers) ----
    hipMemsetAsync(deg, 0, NODES * sizeof(int), stream);
    hist_kernel<<<EB, 256, 0, stream>>>(dst, deg);
    scan_part<<<SCAN_NB, SCAN_BLK, 0, stream>>>(deg, part);
    scan_scan<<<1, SCAN_BLK, 0, stream>>>(part);
    scan_expand<<<SCAN_NB, SCAN_BLK, 0, stream>>>(deg, part, rowstart, cursor);
    scatter_kernel<<<EB, 256, 0, stream>>>(src, dst, cursor, csrc);

    // ---- layer 1 (114 -> 198 -> 198), ping-pong x,b0 -> b1 -> b0 ----
    csr_agg<114, false><<<AB, 256, 0, stream>>>(x, 114, rowstart, csrc, nullptr, nullptr, b0);
    gemm_mfma<114, 198, true, false, false><<<GB64, 256, 0, stream>>>(
        x, 114, b0, WF1, b1a, nullptr, nullptr, b1, nullptr, nullptr);
    hipMemsetAsync(SUM, 0, 512 * sizeof(float), stream);
    gemm_mfma<198, 198, false, true, false><<<GB64, 256, 0, stream>>>(
        b1, P, nullptr, WF2, b1b, nullptr, nullptr, b0, SUM, SQ);
    bn_finalize<198><<<1, 256, 0, stream>>>(SUM, SQ, g1, be1, SCALE, SHIFT);

    // ---- layer 2 (198 -> 64 -> 64); BN1 folded into agg + gemm stage ----
    csr_agg_v4<<<AB, 256, 0, stream>>>(b0, rowstart, csrc, SCALE, SHIFT, b1);
    gemm_mfma<198, 64, true, false, true><<<GB64, 256, 0, stream>>>(
        b0, P, b1, WF3, b2a, SCALE, SHIFT, b1, nullptr, nullptr);
    hipMemsetAsync(SUM, 0, 512 * sizeof(float), stream);
    gemm_mfma<64, 64, false, true, false><<<GB64, 256, 0, stream>>>(
        b1, P, nullptr, WF4, b2b, nullptr, nullptr, b0, SUM, SQ);
    bn_finalize<64><<<1, 256, 0, stream>>>(SUM, SQ, g2, be2, SCALE, SHIFT);

    // ---- layer 3 (64 -> 32 -> 32); BN2 folded ----
    csr_agg<64, true><<<AB, 256, 0, stream>>>(b0, P, rowstart, csrc, SCALE, SHIFT, b1);
    gemm_mfma<64, 32, true, false, true><<<GB64, 256, 0, stream>>>(
        b0, P, b1, WF5, b3a, SCALE, SHIFT, b1, nullptr, nullptr);
    hipMemsetAsync(SUM, 0, 512 * sizeof(float), stream);
    gemm_mfma<32, 32, false, true, false><<<GB64, 256, 0, stream>>>(
        b1, P, nullptr, WF6, b3b, nullptr, nullptr, b0, SUM, SQ);
    bn_finalize<32><<<1, 256, 0, stream>>>(SUM, SQ, g3, be3, SCALE, SHIFT);

    // ---- pool (BN3 folded) + head ----
    hipMemsetAsync(G, 0, GRAPHS * 32 * sizeof(float), stream);
    pool_kernel<<<(NODES * 32 + 255) / 256, 256, 0, stream>>>(b0, batch, SCALE, SHIFT, G);
    head_kernel<<<(GRAPHS + 255) / 256, 256, 0, stream>>>(G, fw1, fb1, fw2, fb2, ow, ob, out);
}

// Round 10
// 614.297 us; speedup vs baseline: 1.7955x; 1.0986x over previous
//
#include <hip/hip_runtime.h>

#define NODES  50000
#define EDGES  800000
#define GRAPHS 1024
#define P      200      // pitch (floats) for 198-wide node buffers

#define SCAN_BLK 256
#define SCAN_NB  ((NODES + SCAN_BLK - 1) / SCAN_BLK)   // 196

typedef __attribute__((ext_vector_type(8))) short short8v;  // 8 bf16 (4 VGPRs)
typedef __attribute__((ext_vector_type(4))) float f32x4;    // MFMA accumulator

__device__ __forceinline__ ushort f2bf(float f) {           // fp32 -> bf16 RNE
    uint u = __float_as_uint(f);
    u = u + 0x7FFFu + ((u >> 16) & 1u);
    return (ushort)(u >> 16);
}

// ---------------------------------------------------------------------------
// CSR build
// ---------------------------------------------------------------------------
__global__ void hist_kernel(const int* __restrict__ dst, int* __restrict__ deg) {
    int e = blockIdx.x * blockDim.x + threadIdx.x;
    if (e < EDGES) atomicAdd(&deg[dst[e]], 1);
}

__global__ void scan_part(const int* __restrict__ deg, int* __restrict__ part) {
    __shared__ int sh[SCAN_BLK];
    int t = threadIdx.x;
    int n = blockIdx.x * SCAN_BLK + t;
    sh[t] = (n < NODES) ? deg[n] : 0;
    __syncthreads();
    for (int off = SCAN_BLK / 2; off > 0; off >>= 1) {
        if (t < off) sh[t] += sh[t + off];
        __syncthreads();
    }
    if (t == 0) part[blockIdx.x] = sh[0];
}

__global__ void scan_scan(int* __restrict__ part) {
    __shared__ int sh[SCAN_BLK];
    int t = threadIdx.x;
    int v = (t < SCAN_NB) ? part[t] : 0;
    sh[t] = v;
    __syncthreads();
    for (int off = 1; off < SCAN_BLK; off <<= 1) {
        int u = 0;
        if (t >= off) u = sh[t - off];
        __syncthreads();
        if (t >= off) sh[t] += u;
        __syncthreads();
    }
    if (t < SCAN_NB) part[t] = sh[t] - v;   // exclusive
}

__global__ void scan_expand(const int* __restrict__ deg, const int* __restrict__ part,
                            int* __restrict__ rowstart, int* __restrict__ cursor) {
    __shared__ int sh[SCAN_BLK];
    int t = threadIdx.x;
    int n = blockIdx.x * SCAN_BLK + t;
    int v = (n < NODES) ? deg[n] : 0;
    sh[t] = v;
    __syncthreads();
    for (int off = 1; off < SCAN_BLK; off <<= 1) {
        int u = 0;
        if (t >= off) u = sh[t - off];
        __syncthreads();
        if (t >= off) sh[t] += u;
        __syncthreads();
    }
    int excl = sh[t] - v + part[blockIdx.x];
    if (n < NODES) {
        rowstart[n] = excl;
        cursor[n]   = excl;
        if (n == NODES - 1) rowstart[NODES] = excl + v;
    }
}

__global__ void scatter_kernel(const int* __restrict__ src, const int* __restrict__ dst,
                               int* __restrict__ cursor, int* __restrict__ csrc) {
    int e = blockIdx.x * blockDim.x + threadIdx.x;
    if (e < EDGES) {
        int p = atomicAdd(&cursor[dst[e]], 1);
        csrc[p] = src[e];
    }
}

// ---------------------------------------------------------------------------
// Weight -> MFMA-fragment-ordered bf16 hi/lo
// ---------------------------------------------------------------------------
__global__ void pad_w_mfma(const float* __restrict__ W, int K, int N, int NCH, int CT,
                           ushort* __restrict__ out) {
    int s = blockIdx.x * blockDim.x + threadIdx.x;
    int half = NCH * CT * 512;
    if (s >= 2 * half) return;
    int h = s / half;
    int r = s % half;
    int j = r & 7, col = (r >> 3) & 15, kg = (r >> 7) & 3;
    int rest = r >> 9;                  // c*CT + ct
    int ct = rest % CT, c = rest / CT;
    int k = c * 32 + kg * 8 + j;
    int n = ct * 16 + col;
    float v = (k < K && n < N) ? W[k * N + n] : 0.0f;
    ushort hi = f2bf(v);
    if (h == 0) out[s] = hi;
    else {
        float hf = __uint_as_float(((uint)hi) << 16);
        out[s] = f2bf(v - hf);
    }
}

// ---------------------------------------------------------------------------
// Aggregation: one wave per dst node, lane-per-column, register accumulation.
// fpitch/opitch runtime (compact storage for post-GEMM aggregation).
// ---------------------------------------------------------------------------
template<int D>
__global__ void csr_agg(const float* __restrict__ feat, int fpitch,
                        const int* __restrict__ rowstart, const int* __restrict__ csrc,
                        float* __restrict__ agg, int opitch) {
    int wid  = (blockIdx.x * blockDim.x + threadIdx.x) >> 6;
    int lane = threadIdx.x & 63;
    if (wid >= NODES) return;
    constexpr int NI = (D + 63) / 64;
    float s[NI];
#pragma unroll
    for (int i = 0; i < NI; i++) s[i] = 0.0f;
    int r0 = rowstart[wid], r1 = rowstart[wid + 1];
    for (int r = r0; r < r1; r++) {
        int sn = csrc[r];
        const float* fp = feat + (size_t)sn * fpitch;
#pragma unroll
        for (int i = 0; i < NI; i++) {
            int c = lane + 64 * i;
            if (c < D) s[i] += fp[c];
        }
    }
    float* ap = agg + (size_t)wid * opitch;
#pragma unroll
    for (int i = 0; i < NI; i++) {
        int c = lane + 64 * i;
        if (c < D) ap[c] = s[i];
    }
}

// ---------------------------------------------------------------------------
// MFMA GEMM, bf16 hi/lo split (fp32-grade, matrix pipe).
//  stage:  v = X[m][k]; if BNX v=v*scale[k]+shift[k]; if ADD2 v+=A2[m][k];
//          if PRE v = relu(v + PREB[k])            (GIN pre-MLP fused here)
//  OUT[m][n] = ACT ? relu(acc + B[n]) : acc        (ACT=0 => linear-only y-GEMM)
// Block = 64 rows x NP cols, 4 waves. A chunk in LDS; W frags direct from L2.
// In-place safe when OUT==X or A2: block reads only own rows before writing.
// ---------------------------------------------------------------------------
template<int K, int N, bool ADD2, bool STATS, bool BNX, bool PRE, bool ACT>
__launch_bounds__(256)
__global__ void gemm_mfma(const float* __restrict__ X, int xpitch,
                          const float* __restrict__ A2, int apitch,
                          const ushort* __restrict__ WF,  // [2][NCH][CT][4][16][8]
                          const float* __restrict__ B,
                          const float* __restrict__ PREB,
                          const float* __restrict__ scale, const float* __restrict__ shift,
                          float* __restrict__ OUT, int opitch,
                          float* __restrict__ gsum, float* __restrict__ gsq) {
    constexpr int KP  = ((K + 31) / 32) * 32;
    constexpr int NCH = KP / 32;
    constexpr int NP  = ((N + 63) / 64) * 64;   // 64 or 256
    constexpr int CT  = NP / 16;
    constexpr int CTW = CT / 4;
    static_assert(CT % 4 == 0, "col tiles must split across 4 waves");

    __shared__ __align__(16) ushort A_lds[2][4][4][16][8]; // [h][rt][kg][row][j]
    __shared__ float shSum[STATS ? NP : 4];
    __shared__ float shSq [STATS ? NP : 4];

    const int tid  = threadIdx.x;
    const int lane = tid & 63;
    const int wv   = tid >> 6;
    const int node0 = blockIdx.x * 64;

    if (STATS) {
        for (int n = tid; n < NP; n += 256) { shSum[n] = 0.0f; shSq[n] = 0.0f; }
    }

    f32x4 acc[4][CTW] = {};

    const int sr  = tid >> 2;   // staging row 0..63
    const int skg = tid & 3;    // staging k-group (8 k's)
    const size_t fstride = (size_t)NCH * CT * 512;

    for (int c = 0; c < NCH; c++) {
        const int kbase = c * 32;
        // ---- stage + convert A chunk (64 x 32) ----
        {
            const int gn = node0 + sr;
            const int k0 = kbase + skg * 8;
            float v[8];
#pragma unroll
            for (int j = 0; j < 8; j++) {
                int gk = k0 + j;
                float t = 0.0f;
                if (gn < NODES && gk < K) {
                    t = X[(size_t)gn * xpitch + gk];
                    if (BNX) t = fmaf(t, scale[gk], shift[gk]);
                    if (ADD2) t += A2[(size_t)gn * apitch + gk];
                    if (PRE)  t = fmaxf(t + PREB[gk], 0.0f);
                }
                v[j] = t;
            }
            short8v hv, lv;
#pragma unroll
            for (int j = 0; j < 8; j++) {
                ushort h = f2bf(v[j]);
                float hf = __uint_as_float(((uint)h) << 16);
                ushort l = f2bf(v[j] - hf);
                hv[j] = (short)h; lv[j] = (short)l;
            }
            *(short8v*)&A_lds[0][sr >> 4][skg][sr & 15][0] = hv;
            *(short8v*)&A_lds[1][sr >> 4][skg][sr & 15][0] = lv;
        }
        __syncthreads();

        // ---- fragments + MFMA ----
        const int kg = lane >> 4, rw = lane & 15;
        short8v ah[4], al[4];
#pragma unroll
        for (int rt = 0; rt < 4; rt++) {
            ah[rt] = *(const short8v*)&A_lds[0][rt][kg][rw][0];
            al[rt] = *(const short8v*)&A_lds[1][rt][kg][rw][0];
        }
#pragma unroll
        for (int t = 0; t < CTW; t++) {
            const int ct = wv * CTW + t;
            const size_t fb = ((size_t)(c * CT + ct)) * 512 + (size_t)lane * 8;
            short8v wh = *(const short8v*)(WF + fb);
            short8v wl = *(const short8v*)(WF + fstride + fb);
#pragma unroll
            for (int rt = 0; rt < 4; rt++) {
                acc[rt][t] = __builtin_amdgcn_mfma_f32_16x16x32_bf16(ah[rt], wh, acc[rt][t], 0, 0, 0);
                acc[rt][t] = __builtin_amdgcn_mfma_f32_16x16x32_bf16(al[rt], wh, acc[rt][t], 0, 0, 0);
                acc[rt][t] = __builtin_amdgcn_mfma_f32_16x16x32_bf16(ah[rt], wl, acc[rt][t], 0, 0, 0);
            }
        }
        __syncthreads();
    }

    // ---- epilogue ----
    const int mg = lane >> 4, colb = lane & 15;
#pragma unroll
    for (int t = 0; t < CTW; t++) {
        const int ct = wv * CTW + t;
        const int n = ct * 16 + colb;
        const float bn = (ACT && n < N) ? B[n] : 0.0f;
        float psum = 0.0f, psq = 0.0f;
#pragma unroll
        for (int rt = 0; rt < 4; rt++) {
#pragma unroll
            for (int j = 0; j < 4; j++) {
                int m = node0 + rt * 16 + mg * 4 + j;
                float vv = ACT ? fmaxf(acc[rt][t][j] + bn, 0.0f) : acc[rt][t][j];
                if (m < NODES && n < N) {
                    OUT[(size_t)m * opitch + n] = vv;
                    if (STATS) { psum += vv; psq += vv * vv; }
                }
            }
        }
        if (STATS && n < N) {
            atomicAdd(&shSum[n], psum);
            atomicAdd(&shSq[n], psq);
        }
    }
    if (STATS) {
        __syncthreads();
        for (int n = tid; n < N; n += 256) {
            atomicAdd(&gsum[n], shSum[n]);
            atomicAdd(&gsq[n], shSq[n]);
        }
    }
}

// ---------------------------------------------------------------------------
// BN finalize (scale/shift for folded apply)
// ---------------------------------------------------------------------------
template<int N>
__global__ void bn_finalize(const float* __restrict__ sum, const float* __restrict__ sq,
                            const float* __restrict__ gamma, const float* __restrict__ beta,
                            float* __restrict__ scale, float* __restrict__ shift) {
    int n = threadIdx.x;
    if (n < N) {
        float mean = sum[n] * (1.0f / NODES);
        float var  = sq[n] * (1.0f / NODES) - mean * mean;
        var = var < 0.0f ? 0.0f : var;
        float sc = gamma[n] * rsqrtf(var + 1e-5f);
        scale[n] = sc;
        shift[n] = beta[n] - mean * sc;
    }
}

// ---------------------------------------------------------------------------
// Pool (BN3 affine folded; h compact pitch 32) + head MLP
// ---------------------------------------------------------------------------
__global__ void pool_kernel(const float* __restrict__ h, const int* __restrict__ batch,
                            const float* __restrict__ scale, const float* __restrict__ shift,
                            float* __restrict__ g) {
    int idx = blockIdx.x * blockDim.x + threadIdx.x;
    if (idx >= NODES * 32) return;
    int n = idx >> 5, f = idx & 31;
    float v = fmaf(h[(size_t)n * 32 + f], scale[f], shift[f]);
    atomicAdd(&g[batch[n] * 32 + f], v);
}

__global__ void head_kernel(const float* __restrict__ g,
                            const float* __restrict__ fw1, const float* __restrict__ fb1,
                            const float* __restrict__ fw2, const float* __restrict__ fb2,
                            const float* __restrict__ ow, const float* __restrict__ ob,
                            float* __restrict__ out) {
    int gi = blockIdx.x * blockDim.x + threadIdx.x;
    if (gi >= GRAPHS) return;
    float v[32];
#pragma unroll
    for (int k = 0; k < 32; k++) v[k] = g[gi * 32 + k];
    float a1[16];
#pragma unroll
    for (int o = 0; o < 16; o++) {
        float s = fb1[o];
#pragma unroll
        for (int k = 0; k < 32; k++) s = fmaf(v[k], fw1[k * 16 + o], s);
        a1[o] = s > 0.0f ? s : 0.0f;
    }
    float a2[8];
#pragma unroll
    for (int o = 0; o < 8; o++) {
        float s = fb2[o];
#pragma unroll
        for (int k = 0; k < 16; k++) s = fmaf(a1[k], fw2[k * 8 + o], s);
        a2[o] = s > 0.0f ? s : 0.0f;
    }
#pragma unroll
    for (int o = 0; o < 2; o++) {
        float s = ob[o];
#pragma unroll
        for (int k = 0; k < 8; k++) s = fmaf(a2[k], ow[k * 2 + o], s);
        out[gi * 2 + o] = s;
    }
}

// ---------------------------------------------------------------------------
extern "C" void kernel_launch(void* const* d_in, const int* in_sizes, int n_in,
                              void* d_out, int out_size, void* d_ws, size_t ws_size,
                              hipStream_t stream) {
    const float* x     = (const float*)d_in[0];
    const int*   ei    = (const int*)d_in[1];
    const int*   batch = (const int*)d_in[2];
    const float *w1a = (const float*)d_in[3],  *b1a = (const float*)d_in[4];
    const float *w1b = (const float*)d_in[5],  *b1b = (const float*)d_in[6];
    const float *g1  = (const float*)d_in[7],  *be1 = (const float*)d_in[8];
    const float *w2a = (const float*)d_in[9],  *b2a = (const float*)d_in[10];
    const float *w2b = (const float*)d_in[11], *b2b = (const float*)d_in[12];
    const float *g2  = (const float*)d_in[13], *be2 = (const float*)d_in[14];
    const float *w3a = (const float*)d_in[15], *b3a = (const float*)d_in[16];
    const float *w3b = (const float*)d_in[17], *b3b = (const float*)d_in[18];
    const float *g3  = (const float*)d_in[19], *be3 = (const float*)d_in[20];
    const float *fw1 = (const float*)d_in[21], *fb1 = (const float*)d_in[22];
    const float *fw2 = (const float*)d_in[23], *fb2 = (const float*)d_in[24];
    const float *ow  = (const float*)d_in[25], *ob  = (const float*)d_in[26];
    const int* src = ei;
    const int* dst = ei + EDGES;

    float* ws    = (float*)d_ws;
    float* b0    = ws;                                  // 50000 x 200
    float* b1    = ws + (size_t)NODES * P;              // 50000 x 200
    float* Y2    = b1;                                  // 50000 x 64 (compact, in b1)
    float* AG2   = b1 + (size_t)NODES * 64;             // 50000 x 64 (compact, in b1)
    float* Y3    = b1;                                  // 50000 x 32 (compact, in b1)
    float* AG3   = b1 + (size_t)NODES * 32;             // 50000 x 32 (compact, in b1)
    float* SUM   = ws + (size_t)2 * NODES * P;          // 256
    float* SQ    = SUM + 256;
    float* SCALE = SUM + 512;
    float* SHIFT = SUM + 768;
    float* G     = SUM + 1024;                          // 1024 x 32
    int*   deg      = (int*)(G + GRAPHS * 32);          // 50000
    int*   rowstart = deg + NODES;                      // 50001
    int*   cursor   = rowstart + NODES + 1;             // 50000
    int*   part     = cursor + NODES;                   // 256 (scan partials)
    int*   csrc     = part + 256;                       // 800000
    uintptr_t wfp = ((uintptr_t)(csrc + EDGES) + 15) & ~(uintptr_t)15;
    ushort* WF1 = (ushort*)wfp;                         // 2*4*16*512  = 65536
    ushort* WF2 = WF1 + 65536;                          // 2*7*16*512  = 114688
    ushort* WF3 = WF2 + 114688;                         // 2*7*4*512   = 28672
    ushort* WF4 = WF3 + 28672;                          // 2*2*4*512   = 8192
    ushort* WF5 = WF4 + 8192;                           // 2*2*4*512   = 8192
    ushort* WF6 = WF5 + 8192;                           // 2*1*4*512   = 4096
    float* out = (float*)d_out;

    const int GB64 = (NODES + 63) / 64;      // 782 gemm blocks
    const int AB = (NODES * 64 + 255) / 256; // agg blocks (wave per node)
    const int EB = (EDGES + 255) / 256;

    // ---- weight conversion to MFMA fragment layout (once per launch) ----
    pad_w_mfma<<<(65536 + 255) / 256, 256, 0, stream>>>(w1a, 114, 198, 4, 16, WF1);
    pad_w_mfma<<<(114688 + 255) / 256, 256, 0, stream>>>(w1b, 198, 198, 7, 16, WF2);
    pad_w_mfma<<<(28672 + 255) / 256, 256, 0, stream>>>(w2a, 198, 64, 7, 4, WF3);
    pad_w_mfma<<<(8192 + 255) / 256, 256, 0, stream>>>(w2b, 64, 64, 2, 4, WF4);
    pad_w_mfma<<<(8192 + 255) / 256, 256, 0, stream>>>(w3a, 64, 32, 2, 4, WF5);
    pad_w_mfma<<<(4096 + 255) / 256, 256, 0, stream>>>(w3b, 32, 32, 1, 4, WF6);

    // ---- CSR build (shared by all 3 layers) ----
    hipMemsetAsync(deg, 0, NODES * sizeof(int), stream);
    hist_kernel<<<EB, 256, 0, stream>>>(dst, deg);
    scan_part<<<SCAN_NB, SCAN_BLK, 0, stream>>>(deg, part);
    scan_scan<<<1, SCAN_BLK, 0, stream>>>(part);
    scan_expand<<<SCAN_NB, SCAN_BLK, 0, stream>>>(deg, part, rowstart, cursor);
    scatter_kernel<<<EB, 256, 0, stream>>>(src, dst, cursor, csrc);

    // ---- layer 1 (114 -> 198 -> 198): aggregate-first (dim expands) ----
    csr_agg<114><<<AB, 256, 0, stream>>>(x, 114, rowstart, csrc, b0, P);
    gemm_mfma<114, 198, true, false, false, false, true><<<GB64, 256, 0, stream>>>(
        x, 114, b0, P, WF1, b1a, nullptr, nullptr, nullptr, b1, P, nullptr, nullptr);
    hipMemsetAsync(SUM, 0, 512 * sizeof(float), stream);
    gemm_mfma<198, 198, false, true, false, false, true><<<GB64, 256, 0, stream>>>(
        b1, P, nullptr, 0, WF2, b1b, nullptr, nullptr, nullptr, b0, P, SUM, SQ);
    bn_finalize<198><<<1, 256, 0, stream>>>(SUM, SQ, g1, be1, SCALE, SHIFT);

    // ---- layer 2 (198 -> 64 -> 64): aggregate-after at D=64 ----
    // y2 = BN1(h1) @ W2a  (linear only, compact pitch 64)
    gemm_mfma<198, 64, false, false, true, false, false><<<GB64, 256, 0, stream>>>(
        b0, P, nullptr, 0, WF3, nullptr, nullptr, SCALE, SHIFT, Y2, 64, nullptr, nullptr);
    csr_agg<64><<<AB, 256, 0, stream>>>(Y2, 64, rowstart, csrc, AG2, 64);
    hipMemsetAsync(SUM, 0, 512 * sizeof(float), stream);
    // h2 = relu( relu(y2 + aggY2 + b2a) @ W2b + b2b ), stats; compact pitch 64
    gemm_mfma<64, 64, true, true, false, true, true><<<GB64, 256, 0, stream>>>(
        Y2, 64, AG2, 64, WF4, b2b, b2a, nullptr, nullptr, b0, 64, SUM, SQ);
    bn_finalize<64><<<1, 256, 0, stream>>>(SUM, SQ, g2, be2, SCALE, SHIFT);

    // ---- layer 3 (64 -> 32 -> 32): aggregate-after at D=32 ----
    gemm_mfma<64, 32, false, false, true, false, false><<<GB64, 256, 0, stream>>>(
        b0, 64, nullptr, 0, WF5, nullptr, nullptr, SCALE, SHIFT, Y3, 32, nullptr, nullptr);
    csr_agg<32><<<AB, 256, 0, stream>>>(Y3, 32, rowstart, csrc, AG3, 32);
    hipMemsetAsync(SUM, 0, 512 * sizeof(float), stream);
    gemm_mfma<32, 32, true, true, false, true, true><<<GB64, 256, 0, stream>>>(
        Y3, 32, AG3, 32, WF6, b3b, b3a, nullptr, nullptr, b0, 32, SUM, SQ);
    bn_finalize<32><<<1, 256, 0, stream>>>(SUM, SQ, g3, be3, SCALE, SHIFT);

    // ---- pool (BN3 folded, pitch 32) + head ----
    hipMemsetAsync(G, 0, GRAPHS * 32 * sizeof(float), stream);
    pool_kernel<<<(NODES * 32 + 255) / 256, 256, 0, stream>>>(b0, batch, SCALE, SHIFT, G);
    head_kernel<<<(GRAPHS + 255) / 256, 256, 0, stream>>>(G, fw1, fb1, fw2, fb2, ow, ob, out);
}

// Round 11
// 500.062 us; speedup vs baseline: 2.2057x; 1.2284x over previous
//
#include <hip/hip_runtime.h>

#define NODES  50000
#define EDGES  800000
#define GRAPHS 1024
#define P      200      // pitch (floats) for 198-wide node buffers

#define SCAN_BLK 256
#define SCAN_NB  ((NODES + SCAN_BLK - 1) / SCAN_BLK)   // 196

typedef __attribute__((ext_vector_type(8))) short short8v;  // 8 bf16 (4 VGPRs)
typedef __attribute__((ext_vector_type(4))) float f32x4;    // MFMA accumulator

__device__ __forceinline__ ushort f2bf(float f) {           // fp32 -> bf16 RNE
    uint u = __float_as_uint(f);
    u = u + 0x7FFFu + ((u >> 16) & 1u);
    return (ushort)(u >> 16);
}

// ---------------------------------------------------------------------------
// CSR build
// ---------------------------------------------------------------------------
__global__ void hist_kernel(const int* __restrict__ dst, int* __restrict__ deg) {
    int e = blockIdx.x * blockDim.x + threadIdx.x;
    if (e < EDGES) atomicAdd(&deg[dst[e]], 1);
}

__global__ void scan_part(const int* __restrict__ deg, int* __restrict__ part) {
    __shared__ int sh[SCAN_BLK];
    int t = threadIdx.x;
    int n = blockIdx.x * SCAN_BLK + t;
    sh[t] = (n < NODES) ? deg[n] : 0;
    __syncthreads();
    for (int off = SCAN_BLK / 2; off > 0; off >>= 1) {
        if (t < off) sh[t] += sh[t + off];
        __syncthreads();
    }
    if (t == 0) part[blockIdx.x] = sh[0];
}

__global__ void scan_scan(int* __restrict__ part) {
    __shared__ int sh[SCAN_BLK];
    int t = threadIdx.x;
    int v = (t < SCAN_NB) ? part[t] : 0;
    sh[t] = v;
    __syncthreads();
    for (int off = 1; off < SCAN_BLK; off <<= 1) {
        int u = 0;
        if (t >= off) u = sh[t - off];
        __syncthreads();
        if (t >= off) sh[t] += u;
        __syncthreads();
    }
    if (t < SCAN_NB) part[t] = sh[t] - v;   // exclusive
}

__global__ void scan_expand(const int* __restrict__ deg, const int* __restrict__ part,
                            int* __restrict__ rowstart, int* __restrict__ cursor) {
    __shared__ int sh[SCAN_BLK];
    int t = threadIdx.x;
    int n = blockIdx.x * SCAN_BLK + t;
    int v = (n < NODES) ? deg[n] : 0;
    sh[t] = v;
    __syncthreads();
    for (int off = 1; off < SCAN_BLK; off <<= 1) {
        int u = 0;
        if (t >= off) u = sh[t - off];
        __syncthreads();
        if (t >= off) sh[t] += u;
        __syncthreads();
    }
    int excl = sh[t] - v + part[blockIdx.x];
    if (n < NODES) {
        rowstart[n] = excl;
        cursor[n]   = excl;
        if (n == NODES - 1) rowstart[NODES] = excl + v;
    }
}

__global__ void scatter_kernel(const int* __restrict__ src, const int* __restrict__ dst,
                               int* __restrict__ cursor, int* __restrict__ csrc) {
    int e = blockIdx.x * blockDim.x + threadIdx.x;
    if (e < EDGES) {
        int p = atomicAdd(&cursor[dst[e]], 1);
        csrc[p] = src[e];
    }
}

// ---------------------------------------------------------------------------
// Weight -> MFMA-fragment-ordered bf16 hi/lo
// ---------------------------------------------------------------------------
__global__ void pad_w_mfma(const float* __restrict__ W, int K, int N, int NCH, int CT,
                           ushort* __restrict__ out) {
    int s = blockIdx.x * blockDim.x + threadIdx.x;
    int half = NCH * CT * 512;
    if (s >= 2 * half) return;
    int h = s / half;
    int r = s % half;
    int j = r & 7, col = (r >> 3) & 15, kg = (r >> 7) & 3;
    int rest = r >> 9;                  // c*CT + ct
    int ct = rest % CT, c = rest / CT;
    int k = c * 32 + kg * 8 + j;
    int n = ct * 16 + col;
    float v = (k < K && n < N) ? W[k * N + n] : 0.0f;
    ushort hi = f2bf(v);
    if (h == 0) out[s] = hi;
    else {
        float hf = __uint_as_float(((uint)hi) << 16);
        out[s] = f2bf(v - hf);
    }
}

// ---------------------------------------------------------------------------
// Aggregation: one wave per dst node, lane-per-column.
// Latency-optimized: 64 edge indices loaded lane-parallel (1 coalesced load),
// broadcast via __shfl; edge loop unrolled UNR deep with independent temps so
// UNR*NI gathers are in flight before the accumulate waitcnt.
// ---------------------------------------------------------------------------
template<int D>
__global__ void csr_agg(const float* __restrict__ feat, int fpitch,
                        const int* __restrict__ rowstart, const int* __restrict__ csrc,
                        float* __restrict__ agg, int opitch) {
    int wid  = (blockIdx.x * blockDim.x + threadIdx.x) >> 6;
    int lane = threadIdx.x & 63;
    if (wid >= NODES) return;
    constexpr int NI  = (D + 63) / 64;
    constexpr int UNR = (NI == 1) ? 8 : 4;     // ~8 loads outstanding either way
    float s[NI];
#pragma unroll
    for (int i = 0; i < NI; i++) s[i] = 0.0f;
    const int r0 = rowstart[wid], r1 = rowstart[wid + 1];
    for (int base = r0; base < r1; base += 64) {
        const int myidx = (base + lane < r1) ? csrc[base + lane] : 0;
        const int cnt = min(64, r1 - base);
        int t = 0;
        for (; t + UNR <= cnt; t += UNR) {
            const float* p[UNR];
#pragma unroll
            for (int u = 0; u < UNR; u++)
                p[u] = feat + (size_t)__shfl(myidx, t + u) * fpitch;
            float v[UNR][NI];
#pragma unroll
            for (int u = 0; u < UNR; u++)
#pragma unroll
                for (int i = 0; i < NI; i++) {
                    int c = lane + 64 * i;
                    if (c < D) v[u][i] = p[u][c];
                }
#pragma unroll
            for (int i = 0; i < NI; i++) {
                int c = lane + 64 * i;
                if (c < D) {
                    float acc = 0.0f;
#pragma unroll
                    for (int u = 0; u < UNR; u++) acc += v[u][i];
                    s[i] += acc;
                }
            }
        }
        for (; t < cnt; t++) {
            const float* fp2 = feat + (size_t)__shfl(myidx, t) * fpitch;
#pragma unroll
            for (int i = 0; i < NI; i++) {
                int c = lane + 64 * i;
                if (c < D) s[i] += fp2[c];
            }
        }
    }
    float* ap = agg + (size_t)wid * opitch;
#pragma unroll
    for (int i = 0; i < NI; i++) {
        int c = lane + 64 * i;
        if (c < D) ap[c] = s[i];
    }
}

// ---------------------------------------------------------------------------
// MFMA GEMM, bf16 hi/lo split (fp32-grade, matrix pipe).
//  stage:  v = X[m][k]; if BNX v=v*scale[k]+shift[k]; if ADD2 v+=A2[m][k];
//          if PRE v = relu(v + PREB[k])            (GIN pre-MLP fused here)
//  OUT[m][n] = ACT ? relu(acc + B[n]) : acc        (ACT=0 => linear-only y-GEMM)
// Block = 64 rows x NP cols, 4 waves. A chunk in LDS; W frags direct from L2.
// In-place safe when OUT==X or A2: block reads only own rows before writing.
// ---------------------------------------------------------------------------
template<int K, int N, bool ADD2, bool STATS, bool BNX, bool PRE, bool ACT>
__launch_bounds__(256)
__global__ void gemm_mfma(const float* __restrict__ X, int xpitch,
                          const float* __restrict__ A2, int apitch,
                          const ushort* __restrict__ WF,  // [2][NCH][CT][4][16][8]
                          const float* __restrict__ B,
                          const float* __restrict__ PREB,
                          const float* __restrict__ scale, const float* __restrict__ shift,
                          float* __restrict__ OUT, int opitch,
                          float* __restrict__ gsum, float* __restrict__ gsq) {
    constexpr int KP  = ((K + 31) / 32) * 32;
    constexpr int NCH = KP / 32;
    constexpr int NP  = ((N + 63) / 64) * 64;   // 64 or 256
    constexpr int CT  = NP / 16;
    constexpr int CTW = CT / 4;
    static_assert(CT % 4 == 0, "col tiles must split across 4 waves");

    __shared__ __align__(16) ushort A_lds[2][4][4][16][8]; // [h][rt][kg][row][j]
    __shared__ float shSum[STATS ? NP : 4];
    __shared__ float shSq [STATS ? NP : 4];

    const int tid  = threadIdx.x;
    const int lane = tid & 63;
    const int wv   = tid >> 6;
    const int node0 = blockIdx.x * 64;

    if (STATS) {
        for (int n = tid; n < NP; n += 256) { shSum[n] = 0.0f; shSq[n] = 0.0f; }
    }

    f32x4 acc[4][CTW] = {};

    const int sr  = tid >> 2;   // staging row 0..63
    const int skg = tid & 3;    // staging k-group (8 k's)
    const size_t fstride = (size_t)NCH * CT * 512;

    for (int c = 0; c < NCH; c++) {
        const int kbase = c * 32;
        // ---- stage + convert A chunk (64 x 32) ----
        {
            const int gn = node0 + sr;
            const int k0 = kbase + skg * 8;
            float v[8];
#pragma unroll
            for (int j = 0; j < 8; j++) {
                int gk = k0 + j;
                float t = 0.0f;
                if (gn < NODES && gk < K) {
                    t = X[(size_t)gn * xpitch + gk];
                    if (BNX) t = fmaf(t, scale[gk], shift[gk]);
                    if (ADD2) t += A2[(size_t)gn * apitch + gk];
                    if (PRE)  t = fmaxf(t + PREB[gk], 0.0f);
                }
                v[j] = t;
            }
            short8v hv, lv;
#pragma unroll
            for (int j = 0; j < 8; j++) {
                ushort h = f2bf(v[j]);
                float hf = __uint_as_float(((uint)h) << 16);
                ushort l = f2bf(v[j] - hf);
                hv[j] = (short)h; lv[j] = (short)l;
            }
            *(short8v*)&A_lds[0][sr >> 4][skg][sr & 15][0] = hv;
            *(short8v*)&A_lds[1][sr >> 4][skg][sr & 15][0] = lv;
        }
        __syncthreads();

        // ---- fragments + MFMA ----
        const int kg = lane >> 4, rw = lane & 15;
        short8v ah[4], al[4];
#pragma unroll
        for (int rt = 0; rt < 4; rt++) {
            ah[rt] = *(const short8v*)&A_lds[0][rt][kg][rw][0];
            al[rt] = *(const short8v*)&A_lds[1][rt][kg][rw][0];
        }
#pragma unroll
        for (int t = 0; t < CTW; t++) {
            const int ct = wv * CTW + t;
            const size_t fb = ((size_t)(c * CT + ct)) * 512 + (size_t)lane * 8;
            short8v wh = *(const short8v*)(WF + fb);
            short8v wl = *(const short8v*)(WF + fstride + fb);
#pragma unroll
            for (int rt = 0; rt < 4; rt++) {
                acc[rt][t] = __builtin_amdgcn_mfma_f32_16x16x32_bf16(ah[rt], wh, acc[rt][t], 0, 0, 0);
                acc[rt][t] = __builtin_amdgcn_mfma_f32_16x16x32_bf16(al[rt], wh, acc[rt][t], 0, 0, 0);
                acc[rt][t] = __builtin_amdgcn_mfma_f32_16x16x32_bf16(ah[rt], wl, acc[rt][t], 0, 0, 0);
            }
        }
        __syncthreads();
    }

    // ---- epilogue ----
    const int mg = lane >> 4, colb = lane & 15;
#pragma unroll
    for (int t = 0; t < CTW; t++) {
        const int ct = wv * CTW + t;
        const int n = ct * 16 + colb;
        const float bn = (ACT && n < N) ? B[n] : 0.0f;
        float psum = 0.0f, psq = 0.0f;
#pragma unroll
        for (int rt = 0; rt < 4; rt++) {
#pragma unroll
            for (int j = 0; j < 4; j++) {
                int m = node0 + rt * 16 + mg * 4 + j;
                float vv = ACT ? fmaxf(acc[rt][t][j] + bn, 0.0f) : acc[rt][t][j];
                if (m < NODES && n < N) {
                    OUT[(size_t)m * opitch + n] = vv;
                    if (STATS) { psum += vv; psq += vv * vv; }
                }
            }
        }
        if (STATS && n < N) {
            atomicAdd(&shSum[n], psum);
            atomicAdd(&shSq[n], psq);
        }
    }
    if (STATS) {
        __syncthreads();
        for (int n = tid; n < N; n += 256) {
            atomicAdd(&gsum[n], shSum[n]);
            atomicAdd(&gsq[n], shSq[n]);
        }
    }
}

// ---------------------------------------------------------------------------
// BN finalize (scale/shift for folded apply)
// ---------------------------------------------------------------------------
template<int N>
__global__ void bn_finalize(const float* __restrict__ sum, const float* __restrict__ sq,
                            const float* __restrict__ gamma, const float* __restrict__ beta,
                            float* __restrict__ scale, float* __restrict__ shift) {
    int n = threadIdx.x;
    if (n < N) {
        float mean = sum[n] * (1.0f / NODES);
        float var  = sq[n] * (1.0f / NODES) - mean * mean;
        var = var < 0.0f ? 0.0f : var;
        float sc = gamma[n] * rsqrtf(var + 1e-5f);
        scale[n] = sc;
        shift[n] = beta[n] - mean * sc;
    }
}

// ---------------------------------------------------------------------------
// Pool (BN3 affine folded; h compact pitch 32) + head MLP
// ---------------------------------------------------------------------------
__global__ void pool_kernel(const float* __restrict__ h, const int* __restrict__ batch,
                            const float* __restrict__ scale, const float* __restrict__ shift,
                            float* __restrict__ g) {
    int idx = blockIdx.x * blockDim.x + threadIdx.x;
    if (idx >= NODES * 32) return;
    int n = idx >> 5, f = idx & 31;
    float v = fmaf(h[(size_t)n * 32 + f], scale[f], shift[f]);
    atomicAdd(&g[batch[n] * 32 + f], v);
}

__global__ void head_kernel(const float* __restrict__ g,
                            const float* __restrict__ fw1, const float* __restrict__ fb1,
                            const float* __restrict__ fw2, const float* __restrict__ fb2,
                            const float* __restrict__ ow, const float* __restrict__ ob,
                            float* __restrict__ out) {
    int gi = blockIdx.x * blockDim.x + threadIdx.x;
    if (gi >= GRAPHS) return;
    float v[32];
#pragma unroll
    for (int k = 0; k < 32; k++) v[k] = g[gi * 32 + k];
    float a1[16];
#pragma unroll
    for (int o = 0; o < 16; o++) {
        float s = fb1[o];
#pragma unroll
        for (int k = 0; k < 32; k++) s = fmaf(v[k], fw1[k * 16 + o], s);
        a1[o] = s > 0.0f ? s : 0.0f;
    }
    float a2[8];
#pragma unroll
    for (int o = 0; o < 8; o++) {
        float s = fb2[o];
#pragma unroll
        for (int k = 0; k < 16; k++) s = fmaf(a1[k], fw2[k * 8 + o], s);
        a2[o] = s > 0.0f ? s : 0.0f;
    }
#pragma unroll
    for (int o = 0; o < 2; o++) {
        float s = ob[o];
#pragma unroll
        for (int k = 0; k < 8; k++) s = fmaf(a2[k], ow[k * 2 + o], s);
        out[gi * 2 + o] = s;
    }
}

// ---------------------------------------------------------------------------
extern "C" void kernel_launch(void* const* d_in, const int* in_sizes, int n_in,
                              void* d_out, int out_size, void* d_ws, size_t ws_size,
                              hipStream_t stream) {
    const float* x     = (const float*)d_in[0];
    const int*   ei    = (const int*)d_in[1];
    const int*   batch = (const int*)d_in[2];
    const float *w1a = (const float*)d_in[3],  *b1a = (const float*)d_in[4];
    const float *w1b = (const float*)d_in[5],  *b1b = (const float*)d_in[6];
    const float *g1  = (const float*)d_in[7],  *be1 = (const float*)d_in[8];
    const float *w2a = (const float*)d_in[9],  *b2a = (const float*)d_in[10];
    const float *w2b = (const float*)d_in[11], *b2b = (const float*)d_in[12];
    const float *g2  = (const float*)d_in[13], *be2 = (const float*)d_in[14];
    const float *w3a = (const float*)d_in[15], *b3a = (const float*)d_in[16];
    const float *w3b = (const float*)d_in[17], *b3b = (const float*)d_in[18];
    const float *g3  = (const float*)d_in[19], *be3 = (const float*)d_in[20];
    const float *fw1 = (const float*)d_in[21], *fb1 = (const float*)d_in[22];
    const float *fw2 = (const float*)d_in[23], *fb2 = (const float*)d_in[24];
    const float *ow  = (const float*)d_in[25], *ob  = (const float*)d_in[26];
    const int* src = ei;
    const int* dst = ei + EDGES;

    float* ws    = (float*)d_ws;
    float* b0    = ws;                                  // 50000 x 200
    float* b1    = ws + (size_t)NODES * P;              // 50000 x 200
    float* Y2    = b1;                                  // 50000 x 64 (compact, in b1)
    float* AG2   = b1 + (size_t)NODES * 64;             // 50000 x 64 (compact, in b1)
    float* Y3    = b1;                                  // 50000 x 32 (compact, in b1)
    float* AG3   = b1 + (size_t)NODES * 32;             // 50000 x 32 (compact, in b1)
    float* SUM   = ws + (size_t)2 * NODES * P;          // 256
    float* SQ    = SUM + 256;
    float* SCALE = SUM + 512;
    float* SHIFT = SUM + 768;
    float* G     = SUM + 1024;                          // 1024 x 32
    int*   deg      = (int*)(G + GRAPHS * 32);          // 50000
    int*   rowstart = deg + NODES;                      // 50001
    int*   cursor   = rowstart + NODES + 1;             // 50000
    int*   part     = cursor + NODES;                   // 256 (scan partials)
    int*   csrc     = part + 256;                       // 800000
    uintptr_t wfp = ((uintptr_t)(csrc + EDGES) + 15) & ~(uintptr_t)15;
    ushort* WF1 = (ushort*)wfp;                         // 2*4*16*512  = 65536
    ushort* WF2 = WF1 + 65536;                          // 2*7*16*512  = 114688
    ushort* WF3 = WF2 + 114688;                         // 2*7*4*512   = 28672
    ushort* WF4 = WF3 + 28672;                          // 2*2*4*512   = 8192
    ushort* WF5 = WF4 + 8192;                           // 2*2*4*512   = 8192
    ushort* WF6 = WF5 + 8192;                           // 2*1*4*512   = 4096
    float* out = (float*)d_out;

    const int GB64 = (NODES + 63) / 64;      // 782 gemm blocks
    const int AB = (NODES * 64 + 255) / 256; // agg blocks (wave per node)
    const int EB = (EDGES + 255) / 256;

    // ---- weight conversion to MFMA fragment layout (once per launch) ----
    pad_w_mfma<<<(65536 + 255) / 256, 256, 0, stream>>>(w1a, 114, 198, 4, 16, WF1);
    pad_w_mfma<<<(114688 + 255) / 256, 256, 0, stream>>>(w1b, 198, 198, 7, 16, WF2);
    pad_w_mfma<<<(28672 + 255) / 256, 256, 0, stream>>>(w2a, 198, 64, 7, 4, WF3);
    pad_w_mfma<<<(8192 + 255) / 256, 256, 0, stream>>>(w2b, 64, 64, 2, 4, WF4);
    pad_w_mfma<<<(8192 + 255) / 256, 256, 0, stream>>>(w3a, 64, 32, 2, 4, WF5);
    pad_w_mfma<<<(4096 + 255) / 256, 256, 0, stream>>>(w3b, 32, 32, 1, 4, WF6);

    // ---- CSR build (shared by all 3 layers) ----
    hipMemsetAsync(deg, 0, NODES * sizeof(int), stream);
    hist_kernel<<<EB, 256, 0, stream>>>(dst, deg);
    scan_part<<<SCAN_NB, SCAN_BLK, 0, stream>>>(deg, part);
    scan_scan<<<1, SCAN_BLK, 0, stream>>>(part);
    scan_expand<<<SCAN_NB, SCAN_BLK, 0, stream>>>(deg, part, rowstart, cursor);
    scatter_kernel<<<EB, 256, 0, stream>>>(src, dst, cursor, csrc);

    // ---- layer 1 (114 -> 198 -> 198): aggregate-first (dim expands) ----
    csr_agg<114><<<AB, 256, 0, stream>>>(x, 114, rowstart, csrc, b0, P);
    gemm_mfma<114, 198, true, false, false, false, true><<<GB64, 256, 0, stream>>>(
        x, 114, b0, P, WF1, b1a, nullptr, nullptr, nullptr, b1, P, nullptr, nullptr);
    hipMemsetAsync(SUM, 0, 512 * sizeof(float), stream);
    gemm_mfma<198, 198, false, true, false, false, true><<<GB64, 256, 0, stream>>>(
        b1, P, nullptr, 0, WF2, b1b, nullptr, nullptr, nullptr, b0, P, SUM, SQ);
    bn_finalize<198><<<1, 256, 0, stream>>>(SUM, SQ, g1, be1, SCALE, SHIFT);

    // ---- layer 2 (198 -> 64 -> 64): aggregate-after at D=64 ----
    gemm_mfma<198, 64, false, false, true, false, false><<<GB64, 256, 0, stream>>>(
        b0, P, nullptr, 0, WF3, nullptr, nullptr, SCALE, SHIFT, Y2, 64, nullptr, nullptr);
    csr_agg<64><<<AB, 256, 0, stream>>>(Y2, 64, rowstart, csrc, AG2, 64);
    hipMemsetAsync(SUM, 0, 512 * sizeof(float), stream);
    gemm_mfma<64, 64, true, true, false, true, true><<<GB64, 256, 0, stream>>>(
        Y2, 64, AG2, 64, WF4, b2b, b2a, nullptr, nullptr, b0, 64, SUM, SQ);
    bn_finalize<64><<<1, 256, 0, stream>>>(SUM, SQ, g2, be2, SCALE, SHIFT);

    // ---- layer 3 (64 -> 32 -> 32): aggregate-after at D=32 ----
    gemm_mfma<64, 32, false, false, true, false, false><<<GB64, 256, 0, stream>>>(
        b0, 64, nullptr, 0, WF5, nullptr, nullptr, SCALE, SHIFT, Y3, 32, nullptr, nullptr);
    csr_agg<32><<<AB, 256, 0, stream>>>(Y3, 32, rowstart, csrc, AG3, 32);
    hipMemsetAsync(SUM, 0, 512 * sizeof(float), stream);
    gemm_mfma<32, 32, true, true, false, true, true><<<GB64, 256, 0, stream>>>(
        Y3, 32, AG3, 32, WF6, b3b, b3a, nullptr, nullptr, b0, 32, SUM, SQ);
    bn_finalize<32><<<1, 256, 0, stream>>>(SUM, SQ, g3, be3, SCALE, SHIFT);

    // ---- pool (BN3 folded, pitch 32) + head ----
    hipMemsetAsync(G, 0, GRAPHS * 32 * sizeof(float), stream);
    pool_kernel<<<(NODES * 32 + 255) / 256, 256, 0, stream>>>(b0, batch, SCALE, SHIFT, G);
    head_kernel<<<(GRAPHS + 255) / 256, 256, 0, stream>>>(G, fw1, fb1, fw2, fb2, ow, ob, out);
}

// Round 12
// 485.303 us; speedup vs baseline: 2.2728x; 1.0304x over previous
//
#include <hip/hip_runtime.h>

#define NODES  50000
#define EDGES  800000
#define GRAPHS 1024
#define P      200      // pitch (floats) for 198-wide node buffers

#define SCAN_BLK 256
#define SCAN_NB  ((NODES + SCAN_BLK - 1) / SCAN_BLK)   // 196

typedef __attribute__((ext_vector_type(8))) short short8v;  // 8 bf16 (4 VGPRs)
typedef __attribute__((ext_vector_type(4))) float f32x4;    // MFMA accumulator

__device__ __forceinline__ ushort f2bf(float f) {           // fp32 -> bf16 RNE
    uint u = __float_as_uint(f);
    u = u + 0x7FFFu + ((u >> 16) & 1u);
    return (ushort)(u >> 16);
}

// ---------------------------------------------------------------------------
// CSR build
// ---------------------------------------------------------------------------
__global__ void hist_kernel(const int* __restrict__ dst, int* __restrict__ deg) {
    int e = blockIdx.x * blockDim.x + threadIdx.x;
    if (e < EDGES) atomicAdd(&deg[dst[e]], 1);
}

__global__ void scan_part(const int* __restrict__ deg, int* __restrict__ part) {
    __shared__ int sh[SCAN_BLK];
    int t = threadIdx.x;
    int n = blockIdx.x * SCAN_BLK + t;
    sh[t] = (n < NODES) ? deg[n] : 0;
    __syncthreads();
    for (int off = SCAN_BLK / 2; off > 0; off >>= 1) {
        if (t < off) sh[t] += sh[t + off];
        __syncthreads();
    }
    if (t == 0) part[blockIdx.x] = sh[0];
}

__global__ void scan_scan(int* __restrict__ part) {
    __shared__ int sh[SCAN_BLK];
    int t = threadIdx.x;
    int v = (t < SCAN_NB) ? part[t] : 0;
    sh[t] = v;
    __syncthreads();
    for (int off = 1; off < SCAN_BLK; off <<= 1) {
        int u = 0;
        if (t >= off) u = sh[t - off];
        __syncthreads();
        if (t >= off) sh[t] += u;
        __syncthreads();
    }
    if (t < SCAN_NB) part[t] = sh[t] - v;   // exclusive
}

__global__ void scan_expand(const int* __restrict__ deg, const int* __restrict__ part,
                            int* __restrict__ rowstart, int* __restrict__ cursor) {
    __shared__ int sh[SCAN_BLK];
    int t = threadIdx.x;
    int n = blockIdx.x * SCAN_BLK + t;
    int v = (n < NODES) ? deg[n] : 0;
    sh[t] = v;
    __syncthreads();
    for (int off = 1; off < SCAN_BLK; off <<= 1) {
        int u = 0;
        if (t >= off) u = sh[t - off];
        __syncthreads();
        if (t >= off) sh[t] += u;
        __syncthreads();
    }
    int excl = sh[t] - v + part[blockIdx.x];
    if (n < NODES) {
        rowstart[n] = excl;
        cursor[n]   = excl;
        if (n == NODES - 1) rowstart[NODES] = excl + v;
    }
}

__global__ void scatter_kernel(const int* __restrict__ src, const int* __restrict__ dst,
                               int* __restrict__ cursor, int* __restrict__ csrc) {
    int e = blockIdx.x * blockDim.x + threadIdx.x;
    if (e < EDGES) {
        int p = atomicAdd(&cursor[dst[e]], 1);
        csrc[p] = src[e];
    }
}

// ---------------------------------------------------------------------------
// Weight -> MFMA-fragment-ordered bf16 hi/lo
// ---------------------------------------------------------------------------
__global__ void pad_w_mfma(const float* __restrict__ W, int K, int N, int NCH, int CT,
                           ushort* __restrict__ out) {
    int s = blockIdx.x * blockDim.x + threadIdx.x;
    int half = NCH * CT * 512;
    if (s >= 2 * half) return;
    int h = s / half;
    int r = s % half;
    int j = r & 7, col = (r >> 3) & 15, kg = (r >> 7) & 3;
    int rest = r >> 9;                  // c*CT + ct
    int ct = rest % CT, c = rest / CT;
    int k = c * 32 + kg * 8 + j;
    int n = ct * 16 + col;
    float v = (k < K && n < N) ? W[k * N + n] : 0.0f;
    ushort hi = f2bf(v);
    if (h == 0) out[s] = hi;
    else {
        float hf = __uint_as_float(((uint)hi) << 16);
        out[s] = f2bf(v - hf);
    }
}

// ---------------------------------------------------------------------------
// Aggregation: one wave per dst node, lane-per-column, ILP-unrolled gathers.
// ---------------------------------------------------------------------------
template<int D>
__global__ void csr_agg(const float* __restrict__ feat, int fpitch,
                        const int* __restrict__ rowstart, const int* __restrict__ csrc,
                        float* __restrict__ agg, int opitch) {
    int wid  = (blockIdx.x * blockDim.x + threadIdx.x) >> 6;
    int lane = threadIdx.x & 63;
    if (wid >= NODES) return;
    constexpr int NI  = (D + 63) / 64;
    constexpr int UNR = (NI == 1) ? 8 : 4;     // ~8 loads outstanding either way
    float s[NI];
#pragma unroll
    for (int i = 0; i < NI; i++) s[i] = 0.0f;
    const int r0 = rowstart[wid], r1 = rowstart[wid + 1];
    for (int base = r0; base < r1; base += 64) {
        const int myidx = (base + lane < r1) ? csrc[base + lane] : 0;
        const int cnt = min(64, r1 - base);
        int t = 0;
        for (; t + UNR <= cnt; t += UNR) {
            const float* p[UNR];
#pragma unroll
            for (int u = 0; u < UNR; u++)
                p[u] = feat + (size_t)__shfl(myidx, t + u) * fpitch;
            float v[UNR][NI];
#pragma unroll
            for (int u = 0; u < UNR; u++)
#pragma unroll
                for (int i = 0; i < NI; i++) {
                    int c = lane + 64 * i;
                    if (c < D) v[u][i] = p[u][c];
                }
#pragma unroll
            for (int i = 0; i < NI; i++) {
                int c = lane + 64 * i;
                if (c < D) {
                    float acc = 0.0f;
#pragma unroll
                    for (int u = 0; u < UNR; u++) acc += v[u][i];
                    s[i] += acc;
                }
            }
        }
        for (; t < cnt; t++) {
            const float* fp2 = feat + (size_t)__shfl(myidx, t) * fpitch;
#pragma unroll
            for (int i = 0; i < NI; i++) {
                int c = lane + 64 * i;
                if (c < D) s[i] += fp2[c];
            }
        }
    }
    float* ap = agg + (size_t)wid * opitch;
#pragma unroll
    for (int i = 0; i < NI; i++) {
        int c = lane + 64 * i;
        if (c < D) ap[c] = s[i];
    }
}

// ---------------------------------------------------------------------------
// MFMA GEMM, bf16 hi/lo split (fp32-grade, matrix pipe), pipelined:
//  - double-buffered A_lds -> ONE barrier per K-chunk
//  - A chunk c+1 global loads issued before MFMA of chunk c (T14 split);
//    convert + LDS write after MFMA (registers stay small: 8-16 floats)
//  - W fragment (hi/lo) register prefetch one col-tile ahead
//  - s_setprio(1) around the MFMA cluster
//  stage:  v = X[m][k]; if BNX v=v*scale[k]+shift[k]; if ADD2 v+=A2[m][k];
//          if PRE v = relu(v + PREB[k])
//  OUT[m][n] = ACT ? relu(acc + B[n]) : acc
// In-place safe when OUT==X or A2: block reads only own rows before writing.
// ---------------------------------------------------------------------------
template<int K, int N, bool ADD2, bool STATS, bool BNX, bool PRE, bool ACT>
__launch_bounds__(256)
__global__ void gemm_mfma(const float* __restrict__ X, int xpitch,
                          const float* __restrict__ A2, int apitch,
                          const ushort* __restrict__ WF,  // [2][NCH][CT][4][16][8]
                          const float* __restrict__ B,
                          const float* __restrict__ PREB,
                          const float* __restrict__ scale, const float* __restrict__ shift,
                          float* __restrict__ OUT, int opitch,
                          float* __restrict__ gsum, float* __restrict__ gsq) {
    constexpr int KP  = ((K + 31) / 32) * 32;
    constexpr int NCH = KP / 32;
    constexpr int NP  = ((N + 63) / 64) * 64;   // 64 or 256
    constexpr int CT  = NP / 16;
    constexpr int CTW = CT / 4;
    static_assert(CT % 4 == 0, "col tiles must split across 4 waves");

    __shared__ __align__(16) ushort A_lds[2][2][4][4][16][8]; // [buf][h][rt][kg][row][j]
    __shared__ float shSum[STATS ? NP : 4];
    __shared__ float shSq [STATS ? NP : 4];

    const int tid  = threadIdx.x;
    const int lane = tid & 63;
    const int wv   = tid >> 6;
    const int node0 = blockIdx.x * 64;

    if (STATS) {
        for (int n = tid; n < NP; n += 256) { shSum[n] = 0.0f; shSq[n] = 0.0f; }
    }

    f32x4 acc[4][CTW] = {};

    const int sr  = tid >> 2;   // staging row 0..63
    const int skg = tid & 3;    // staging k-group (8 k's)
    const int gn  = node0 + sr;
    const size_t fstride = (size_t)NCH * CT * 512;

    float xv[8];
    float a2v[ADD2 ? 8 : 1];

    auto loadA = [&](int c) {                 // global loads only (issue early)
        const int k0 = c * 32 + skg * 8;
#pragma unroll
        for (int j = 0; j < 8; j++) {
            int gk = k0 + j;
            bool ok = (gn < NODES && gk < K);
            xv[j] = ok ? X[(size_t)gn * xpitch + gk] : 0.0f;
            if (ADD2) a2v[j] = ok ? A2[(size_t)gn * apitch + gk] : 0.0f;
        }
    };
    auto cvtStoreA = [&](int buf, int c) {    // VALU convert + LDS write (late)
        const int k0 = c * 32 + skg * 8;
        short8v hv, lv;
#pragma unroll
        for (int j = 0; j < 8; j++) {
            int gk = k0 + j;
            float t = 0.0f;
            if (gn < NODES && gk < K) {
                t = xv[j];
                if (BNX) t = fmaf(t, scale[gk], shift[gk]);
                if (ADD2) t += a2v[j];
                if (PRE)  t = fmaxf(t + PREB[gk], 0.0f);
            }
            ushort h = f2bf(t);
            float hf = __uint_as_float(((uint)h) << 16);
            ushort l = f2bf(t - hf);
            hv[j] = (short)h; lv[j] = (short)l;
        }
        *(short8v*)&A_lds[buf][0][sr >> 4][skg][sr & 15][0] = hv;
        *(short8v*)&A_lds[buf][1][sr >> 4][skg][sr & 15][0] = lv;
    };

    loadA(0);
    cvtStoreA(0, 0);
    __syncthreads();

    const int kg = lane >> 4, rw = lane & 15;
    for (int c = 0; c < NCH; c++) {
        const int buf = c & 1;
        if (c + 1 < NCH) loadA(c + 1);        // next A chunk: loads in flight

        short8v ah[4], al[4];
#pragma unroll
        for (int rt = 0; rt < 4; rt++) {
            ah[rt] = *(const short8v*)&A_lds[buf][0][rt][kg][rw][0];
            al[rt] = *(const short8v*)&A_lds[buf][1][rt][kg][rw][0];
        }

        const size_t fb0 = ((size_t)(c * CT + wv * CTW)) * 512 + (size_t)lane * 8;
        short8v wh = *(const short8v*)(WF + fb0);
        short8v wl = *(const short8v*)(WF + fstride + fb0);
#pragma unroll
        for (int t = 0; t < CTW; t++) {
            short8v nwh, nwl;
            if (t + 1 < CTW) {                // prefetch next col-tile's W
                const size_t fb = fb0 + (size_t)(t + 1) * 512;
                nwh = *(const short8v*)(WF + fb);
                nwl = *(const short8v*)(WF + fstride + fb);
            }
            __builtin_amdgcn_s_setprio(1);
#pragma unroll
            for (int rt = 0; rt < 4; rt++) {
                acc[rt][t] = __builtin_amdgcn_mfma_f32_16x16x32_bf16(ah[rt], wh, acc[rt][t], 0, 0, 0);
                acc[rt][t] = __builtin_amdgcn_mfma_f32_16x16x32_bf16(al[rt], wh, acc[rt][t], 0, 0, 0);
                acc[rt][t] = __builtin_amdgcn_mfma_f32_16x16x32_bf16(ah[rt], wl, acc[rt][t], 0, 0, 0);
            }
            __builtin_amdgcn_s_setprio(0);
            if (t + 1 < CTW) { wh = nwh; wl = nwl; }
        }

        if (c + 1 < NCH) cvtStoreA((c + 1) & 1, c + 1);  // write other buffer
        __syncthreads();                       // single barrier per chunk
    }

    // ---- epilogue: bias, relu, store, stats ----
    const int mg = lane >> 4, colb = lane & 15;
#pragma unroll
    for (int t = 0; t < CTW; t++) {
        const int ct = wv * CTW + t;
        const int n = ct * 16 + colb;
        const float bn = (ACT && n < N) ? B[n] : 0.0f;
        float psum = 0.0f, psq = 0.0f;
#pragma unroll
        for (int rt = 0; rt < 4; rt++) {
#pragma unroll
            for (int j = 0; j < 4; j++) {
                int m = node0 + rt * 16 + mg * 4 + j;
                float vv = ACT ? fmaxf(acc[rt][t][j] + bn, 0.0f) : acc[rt][t][j];
                if (m < NODES && n < N) {
                    OUT[(size_t)m * opitch + n] = vv;
                    if (STATS) { psum += vv; psq += vv * vv; }
                }
            }
        }
        if (STATS && n < N) {
            atomicAdd(&shSum[n], psum);
            atomicAdd(&shSq[n], psq);
        }
    }
    if (STATS) {
        __syncthreads();
        for (int n = tid; n < N; n += 256) {
            atomicAdd(&gsum[n], shSum[n]);
            atomicAdd(&gsq[n], shSq[n]);
        }
    }
}

// ---------------------------------------------------------------------------
// BN finalize (scale/shift for folded apply)
// ---------------------------------------------------------------------------
template<int N>
__global__ void bn_finalize(const float* __restrict__ sum, const float* __restrict__ sq,
                            const float* __restrict__ gamma, const float* __restrict__ beta,
                            float* __restrict__ scale, float* __restrict__ shift) {
    int n = threadIdx.x;
    if (n < N) {
        float mean = sum[n] * (1.0f / NODES);
        float var  = sq[n] * (1.0f / NODES) - mean * mean;
        var = var < 0.0f ? 0.0f : var;
        float sc = gamma[n] * rsqrtf(var + 1e-5f);
        scale[n] = sc;
        shift[n] = beta[n] - mean * sc;
    }
}

// ---------------------------------------------------------------------------
// Pool (BN3 affine folded; h compact pitch 32) + head MLP
// ---------------------------------------------------------------------------
__global__ void pool_kernel(const float* __restrict__ h, const int* __restrict__ batch,
                            const float* __restrict__ scale, const float* __restrict__ shift,
                            float* __restrict__ g) {
    int idx = blockIdx.x * blockDim.x + threadIdx.x;
    if (idx >= NODES * 32) return;
    int n = idx >> 5, f = idx & 31;
    float v = fmaf(h[(size_t)n * 32 + f], scale[f], shift[f]);
    atomicAdd(&g[batch[n] * 32 + f], v);
}

__global__ void head_kernel(const float* __restrict__ g,
                            const float* __restrict__ fw1, const float* __restrict__ fb1,
                            const float* __restrict__ fw2, const float* __restrict__ fb2,
                            const float* __restrict__ ow, const float* __restrict__ ob,
                            float* __restrict__ out) {
    int gi = blockIdx.x * blockDim.x + threadIdx.x;
    if (gi >= GRAPHS) return;
    float v[32];
#pragma unroll
    for (int k = 0; k < 32; k++) v[k] = g[gi * 32 + k];
    float a1[16];
#pragma unroll
    for (int o = 0; o < 16; o++) {
        float s = fb1[o];
#pragma unroll
        for (int k = 0; k < 32; k++) s = fmaf(v[k], fw1[k * 16 + o], s);
        a1[o] = s > 0.0f ? s : 0.0f;
    }
    float a2[8];
#pragma unroll
    for (int o = 0; o < 8; o++) {
        float s = fb2[o];
#pragma unroll
        for (int k = 0; k < 16; k++) s = fmaf(a1[k], fw2[k * 8 + o], s);
        a2[o] = s > 0.0f ? s : 0.0f;
    }
#pragma unroll
    for (int o = 0; o < 2; o++) {
        float s = ob[o];
#pragma unroll
        for (int k = 0; k < 8; k++) s = fmaf(a2[k], ow[k * 2 + o], s);
        out[gi * 2 + o] = s;
    }
}

// ---------------------------------------------------------------------------
extern "C" void kernel_launch(void* const* d_in, const int* in_sizes, int n_in,
                              void* d_out, int out_size, void* d_ws, size_t ws_size,
                              hipStream_t stream) {
    const float* x     = (const float*)d_in[0];
    const int*   ei    = (const int*)d_in[1];
    const int*   batch = (const int*)d_in[2];
    const float *w1a = (const float*)d_in[3],  *b1a = (const float*)d_in[4];
    const float *w1b = (const float*)d_in[5],  *b1b = (const float*)d_in[6];
    const float *g1  = (const float*)d_in[7],  *be1 = (const float*)d_in[8];
    const float *w2a = (const float*)d_in[9],  *b2a = (const float*)d_in[10];
    const float *w2b = (const float*)d_in[11], *b2b = (const float*)d_in[12];
    const float *g2  = (const float*)d_in[13], *be2 = (const float*)d_in[14];
    const float *w3a = (const float*)d_in[15], *b3a = (const float*)d_in[16];
    const float *w3b = (const float*)d_in[17], *b3b = (const float*)d_in[18];
    const float *g3  = (const float*)d_in[19], *be3 = (const float*)d_in[20];
    const float *fw1 = (const float*)d_in[21], *fb1 = (const float*)d_in[22];
    const float *fw2 = (const float*)d_in[23], *fb2 = (const float*)d_in[24];
    const float *ow  = (const float*)d_in[25], *ob  = (const float*)d_in[26];
    const int* src = ei;
    const int* dst = ei + EDGES;

    float* ws    = (float*)d_ws;
    float* b0    = ws;                                  // 50000 x 200
    float* b1    = ws + (size_t)NODES * P;              // 50000 x 200
    float* Y2    = b1;                                  // 50000 x 64 (compact, in b1)
    float* AG2   = b1 + (size_t)NODES * 64;             // 50000 x 64 (compact, in b1)
    float* Y3    = b1;                                  // 50000 x 32 (compact, in b1)
    float* AG3   = b1 + (size_t)NODES * 32;             // 50000 x 32 (compact, in b1)
    float* SUM   = ws + (size_t)2 * NODES * P;          // 256
    float* SQ    = SUM + 256;
    float* SCALE = SUM + 512;
    float* SHIFT = SUM + 768;
    float* G     = SUM + 1024;                          // 1024 x 32
    int*   deg      = (int*)(G + GRAPHS * 32);          // 50000
    int*   rowstart = deg + NODES;                      // 50001
    int*   cursor   = rowstart + NODES + 1;             // 50000
    int*   part     = cursor + NODES;                   // 256 (scan partials)
    int*   csrc     = part + 256;                       // 800000
    uintptr_t wfp = ((uintptr_t)(csrc + EDGES) + 15) & ~(uintptr_t)15;
    ushort* WF1 = (ushort*)wfp;                         // 2*4*16*512  = 65536
    ushort* WF2 = WF1 + 65536;                          // 2*7*16*512  = 114688
    ushort* WF3 = WF2 + 114688;                         // 2*7*4*512   = 28672
    ushort* WF4 = WF3 + 28672;                          // 2*2*4*512   = 8192
    ushort* WF5 = WF4 + 8192;                           // 2*2*4*512   = 8192
    ushort* WF6 = WF5 + 8192;                           // 2*1*4*512   = 4096
    float* out = (float*)d_out;

    const int GB64 = (NODES + 63) / 64;      // 782 gemm blocks
    const int AB = (NODES * 64 + 255) / 256; // agg blocks (wave per node)
    const int EB = (EDGES + 255) / 256;

    // ---- weight conversion to MFMA fragment layout (once per launch) ----
    pad_w_mfma<<<(65536 + 255) / 256, 256, 0, stream>>>(w1a, 114, 198, 4, 16, WF1);
    pad_w_mfma<<<(114688 + 255) / 256, 256, 0, stream>>>(w1b, 198, 198, 7, 16, WF2);
    pad_w_mfma<<<(28672 + 255) / 256, 256, 0, stream>>>(w2a, 198, 64, 7, 4, WF3);
    pad_w_mfma<<<(8192 + 255) / 256, 256, 0, stream>>>(w2b, 64, 64, 2, 4, WF4);
    pad_w_mfma<<<(8192 + 255) / 256, 256, 0, stream>>>(w3a, 64, 32, 2, 4, WF5);
    pad_w_mfma<<<(4096 + 255) / 256, 256, 0, stream>>>(w3b, 32, 32, 1, 4, WF6);

    // ---- CSR build (shared by all 3 layers) ----
    hipMemsetAsync(deg, 0, NODES * sizeof(int), stream);
    hist_kernel<<<EB, 256, 0, stream>>>(dst, deg);
    scan_part<<<SCAN_NB, SCAN_BLK, 0, stream>>>(deg, part);
    scan_scan<<<1, SCAN_BLK, 0, stream>>>(part);
    scan_expand<<<SCAN_NB, SCAN_BLK, 0, stream>>>(deg, part, rowstart, cursor);
    scatter_kernel<<<EB, 256, 0, stream>>>(src, dst, cursor, csrc);

    // ---- layer 1 (114 -> 198 -> 198): aggregate-first (dim expands) ----
    csr_agg<114><<<AB, 256, 0, stream>>>(x, 114, rowstart, csrc, b0, P);
    gemm_mfma<114, 198, true, false, false, false, true><<<GB64, 256, 0, stream>>>(
        x, 114, b0, P, WF1, b1a, nullptr, nullptr, nullptr, b1, P, nullptr, nullptr);
    hipMemsetAsync(SUM, 0, 512 * sizeof(float), stream);
    gemm_mfma<198, 198, false, true, false, false, true><<<GB64, 256, 0, stream>>>(
        b1, P, nullptr, 0, WF2, b1b, nullptr, nullptr, nullptr, b0, P, SUM, SQ);
    bn_finalize<198><<<1, 256, 0, stream>>>(SUM, SQ, g1, be1, SCALE, SHIFT);

    // ---- layer 2 (198 -> 64 -> 64): aggregate-after at D=64 ----
    gemm_mfma<198, 64, false, false, true, false, false><<<GB64, 256, 0, stream>>>(
        b0, P, nullptr, 0, WF3, nullptr, nullptr, SCALE, SHIFT, Y2, 64, nullptr, nullptr);
    csr_agg<64><<<AB, 256, 0, stream>>>(Y2, 64, rowstart, csrc, AG2, 64);
    hipMemsetAsync(SUM, 0, 512 * sizeof(float), stream);
    gemm_mfma<64, 64, true, true, false, true, true><<<GB64, 256, 0, stream>>>(
        Y2, 64, AG2, 64, WF4, b2b, b2a, nullptr, nullptr, b0, 64, SUM, SQ);
    bn_finalize<64><<<1, 256, 0, stream>>>(SUM, SQ, g2, be2, SCALE, SHIFT);

    // ---- layer 3 (64 -> 32 -> 32): aggregate-after at D=32 ----
    gemm_mfma<64, 32, false, false, true, false, false><<<GB64, 256, 0, stream>>>(
        b0, 64, nullptr, 0, WF5, nullptr, nullptr, SCALE, SHIFT, Y3, 32, nullptr, nullptr);
    csr_agg<32><<<AB, 256, 0, stream>>>(Y3, 32, rowstart, csrc, AG3, 32);
    hipMemsetAsync(SUM, 0, 512 * sizeof(float), stream);
    gemm_mfma<32, 32, true, true, false, true, true><<<GB64, 256, 0, stream>>>(
        Y3, 32, AG3, 32, WF6, b3b, b3a, nullptr, nullptr, b0, 32, SUM, SQ);
    bn_finalize<32><<<1, 256, 0, stream>>>(SUM, SQ, g3, be3, SCALE, SHIFT);

    // ---- pool (BN3 folded, pitch 32) + head ----
    hipMemsetAsync(G, 0, GRAPHS * 32 * sizeof(float), stream);
    pool_kernel<<<(NODES * 32 + 255) / 256, 256, 0, stream>>>(b0, batch, SCALE, SHIFT, G);
    head_kernel<<<(GRAPHS + 255) / 256, 256, 0, stream>>>(G, fw1, fb1, fw2, fb2, ow, ob, out);
}

// Round 13
// 482.867 us; speedup vs baseline: 2.2842x; 1.0050x over previous
//
#include <hip/hip_runtime.h>

#define NODES  50000
#define EDGES  800000
#define GRAPHS 1024
#define P      200      // pitch (floats) for 198-wide node buffers

#define SCAN_BLK 256
#define SCAN_NB  ((NODES + SCAN_BLK - 1) / SCAN_BLK)   // 196

typedef __attribute__((ext_vector_type(8))) short short8v;  // 8 bf16 (4 VGPRs)
typedef __attribute__((ext_vector_type(4))) short short4v;  // 4 bf16 (2 VGPRs)
typedef __attribute__((ext_vector_type(4))) float f32x4;    // MFMA accumulator

__device__ __forceinline__ ushort f2bf(float f) {           // fp32 -> bf16 RNE
    uint u = __float_as_uint(f);
    u = u + 0x7FFFu + ((u >> 16) & 1u);
    return (ushort)(u >> 16);
}

// ---------------------------------------------------------------------------
// CSR build
// ---------------------------------------------------------------------------
__global__ void hist_kernel(const int* __restrict__ dst, int* __restrict__ deg) {
    int e = blockIdx.x * blockDim.x + threadIdx.x;
    if (e < EDGES) atomicAdd(&deg[dst[e]], 1);
}

__global__ void scan_part(const int* __restrict__ deg, int* __restrict__ part) {
    __shared__ int sh[SCAN_BLK];
    int t = threadIdx.x;
    int n = blockIdx.x * SCAN_BLK + t;
    sh[t] = (n < NODES) ? deg[n] : 0;
    __syncthreads();
    for (int off = SCAN_BLK / 2; off > 0; off >>= 1) {
        if (t < off) sh[t] += sh[t + off];
        __syncthreads();
    }
    if (t == 0) part[blockIdx.x] = sh[0];
}

__global__ void scan_scan(int* __restrict__ part) {
    __shared__ int sh[SCAN_BLK];
    int t = threadIdx.x;
    int v = (t < SCAN_NB) ? part[t] : 0;
    sh[t] = v;
    __syncthreads();
    for (int off = 1; off < SCAN_BLK; off <<= 1) {
        int u = 0;
        if (t >= off) u = sh[t - off];
        __syncthreads();
        if (t >= off) sh[t] += u;
        __syncthreads();
    }
    if (t < SCAN_NB) part[t] = sh[t] - v;   // exclusive
}

__global__ void scan_expand(const int* __restrict__ deg, const int* __restrict__ part,
                            int* __restrict__ rowstart, int* __restrict__ cursor) {
    __shared__ int sh[SCAN_BLK];
    int t = threadIdx.x;
    int n = blockIdx.x * SCAN_BLK + t;
    int v = (n < NODES) ? deg[n] : 0;
    sh[t] = v;
    __syncthreads();
    for (int off = 1; off < SCAN_BLK; off <<= 1) {
        int u = 0;
        if (t >= off) u = sh[t - off];
        __syncthreads();
        if (t >= off) sh[t] += u;
        __syncthreads();
    }
    int excl = sh[t] - v + part[blockIdx.x];
    if (n < NODES) {
        rowstart[n] = excl;
        cursor[n]   = excl;
        if (n == NODES - 1) rowstart[NODES] = excl + v;
    }
}

__global__ void scatter_kernel(const int* __restrict__ src, const int* __restrict__ dst,
                               int* __restrict__ cursor, int* __restrict__ csrc) {
    int e = blockIdx.x * blockDim.x + threadIdx.x;
    if (e < EDGES) {
        int p = atomicAdd(&cursor[dst[e]], 1);
        csrc[p] = src[e];
    }
}

// ---------------------------------------------------------------------------
// Weight -> MFMA-fragment-ordered bf16 hi/lo
// ---------------------------------------------------------------------------
__global__ void pad_w_mfma(const float* __restrict__ W, int K, int N, int NCH, int CT,
                           ushort* __restrict__ out) {
    int s = blockIdx.x * blockDim.x + threadIdx.x;
    int half = NCH * CT * 512;
    if (s >= 2 * half) return;
    int h = s / half;
    int r = s % half;
    int j = r & 7, col = (r >> 3) & 15, kg = (r >> 7) & 3;
    int rest = r >> 9;                  // c*CT + ct
    int ct = rest % CT, c = rest / CT;
    int k = c * 32 + kg * 8 + j;
    int n = ct * 16 + col;
    float v = (k < K && n < N) ? W[k * N + n] : 0.0f;
    ushort hi = f2bf(v);
    if (h == 0) out[s] = hi;
    else {
        float hf = __uint_as_float(((uint)hi) << 16);
        out[s] = f2bf(v - hf);
    }
}

// ---------------------------------------------------------------------------
// Aggregation: one wave per dst node, lane-per-column, ILP-unrolled gathers.
// ---------------------------------------------------------------------------
template<int D>
__global__ void csr_agg(const float* __restrict__ feat, int fpitch,
                        const int* __restrict__ rowstart, const int* __restrict__ csrc,
                        float* __restrict__ agg, int opitch) {
    int wid  = (blockIdx.x * blockDim.x + threadIdx.x) >> 6;
    int lane = threadIdx.x & 63;
    if (wid >= NODES) return;
    constexpr int NI  = (D + 63) / 64;
    constexpr int UNR = 8;                     // 8*NI gathers in flight
    float s[NI];
#pragma unroll
    for (int i = 0; i < NI; i++) s[i] = 0.0f;
    const int r0 = rowstart[wid], r1 = rowstart[wid + 1];
    for (int base = r0; base < r1; base += 64) {
        const int myidx = (base + lane < r1) ? csrc[base + lane] : 0;
        const int cnt = min(64, r1 - base);
        int t = 0;
        for (; t + UNR <= cnt; t += UNR) {
            const float* p[UNR];
#pragma unroll
            for (int u = 0; u < UNR; u++)
                p[u] = feat + (size_t)__shfl(myidx, t + u) * fpitch;
            float v[UNR][NI];
#pragma unroll
            for (int u = 0; u < UNR; u++)
#pragma unroll
                for (int i = 0; i < NI; i++) {
                    int c = lane + 64 * i;
                    if (c < D) v[u][i] = p[u][c];
                }
#pragma unroll
            for (int i = 0; i < NI; i++) {
                int c = lane + 64 * i;
                if (c < D) {
                    float acc = 0.0f;
#pragma unroll
                    for (int u = 0; u < UNR; u++) acc += v[u][i];
                    s[i] += acc;
                }
            }
        }
        for (; t < cnt; t++) {
            const float* fp2 = feat + (size_t)__shfl(myidx, t) * fpitch;
#pragma unroll
            for (int i = 0; i < NI; i++) {
                int c = lane + 64 * i;
                if (c < D) s[i] += fp2[c];
            }
        }
    }
    float* ap = agg + (size_t)wid * opitch;
#pragma unroll
    for (int i = 0; i < NI; i++) {
        int c = lane + 64 * i;
        if (c < D) ap[c] = s[i];
    }
}

// ---------------------------------------------------------------------------
// MFMA GEMM, bf16 hi/lo split (fp32-grade, matrix pipe), pipelined.
// 32-ROW blocks (grid 1563 = 6 blocks/CU of work -> latency overlap across
// independent blocks; r12's 64-row/782-block version was block-starved).
//  - double-buffered A_lds, ONE barrier per K-chunk
//  - A chunk c+1 global loads issued before MFMA of chunk c; convert+LDS
//    write after MFMA (4 floats/thread -> tiny register cost)
//  - W fragment register prefetch one col-tile ahead
//  stage:  v = X[m][k]; if BNX v=v*scale[k]+shift[k]; if ADD2 v+=A2[m][k];
//          if PRE v = relu(v + PREB[k])
//  OUT[m][n] = ACT ? relu(acc + B[n]) : acc
// ---------------------------------------------------------------------------
template<int K, int N, bool ADD2, bool STATS, bool BNX, bool PRE, bool ACT>
__launch_bounds__(256)
__global__ void gemm_mfma(const float* __restrict__ X, int xpitch,
                          const float* __restrict__ A2, int apitch,
                          const ushort* __restrict__ WF,  // [2][NCH][CT][4][16][8]
                          const float* __restrict__ B,
                          const float* __restrict__ PREB,
                          const float* __restrict__ scale, const float* __restrict__ shift,
                          float* __restrict__ OUT, int opitch,
                          float* __restrict__ gsum, float* __restrict__ gsq) {
    constexpr int KP  = ((K + 31) / 32) * 32;
    constexpr int NCH = KP / 32;
    constexpr int NP  = ((N + 63) / 64) * 64;   // 64 or 256
    constexpr int CT  = NP / 16;
    constexpr int CTW = CT / 4;
    static_assert(CT % 4 == 0, "col tiles must split across 4 waves");

    __shared__ __align__(16) ushort A_lds[2][2][2][4][16][8]; // [buf][h][rt][kg][row][j]
    __shared__ float shSum[STATS ? NP : 4];
    __shared__ float shSq [STATS ? NP : 4];

    const int tid  = threadIdx.x;
    const int lane = tid & 63;
    const int wv   = tid >> 6;
    const int node0 = blockIdx.x * 32;

    if (STATS) {
        for (int n = tid; n < NP; n += 256) { shSum[n] = 0.0f; shSq[n] = 0.0f; }
    }

    f32x4 acc[2][CTW] = {};

    const int sr  = tid >> 3;           // staging row 0..31
    const int sc4 = (tid & 7) * 4;      // staging col quad (4 k's)
    const int skg = sc4 >> 3;           // k-group
    const int sj0 = sc4 & 7;            // j offset (0 or 4)
    const int gn  = node0 + sr;
    const size_t fstride = (size_t)NCH * CT * 512;

    float xv[4];
    float a2v[ADD2 ? 4 : 1];

    auto loadA = [&](int c) {                 // global loads only (issue early)
        const int k0 = c * 32 + sc4;
#pragma unroll
        for (int j = 0; j < 4; j++) {
            int gk = k0 + j;
            bool ok = (gn < NODES && gk < K);
            xv[j] = ok ? X[(size_t)gn * xpitch + gk] : 0.0f;
            if (ADD2) a2v[j] = ok ? A2[(size_t)gn * apitch + gk] : 0.0f;
        }
    };
    auto cvtStoreA = [&](int buf, int c) {    // VALU convert + LDS write (late)
        const int k0 = c * 32 + sc4;
        short4v hv, lv;
#pragma unroll
        for (int j = 0; j < 4; j++) {
            int gk = k0 + j;
            float t = 0.0f;
            if (gn < NODES && gk < K) {
                t = xv[j];
                if (BNX) t = fmaf(t, scale[gk], shift[gk]);
                if (ADD2) t += a2v[j];
                if (PRE)  t = fmaxf(t + PREB[gk], 0.0f);
            }
            ushort h = f2bf(t);
            float hf = __uint_as_float(((uint)h) << 16);
            ushort l = f2bf(t - hf);
            hv[j] = (short)h; lv[j] = (short)l;
        }
        *(short4v*)&A_lds[buf][0][sr >> 4][skg][sr & 15][sj0] = hv;
        *(short4v*)&A_lds[buf][1][sr >> 4][skg][sr & 15][sj0] = lv;
    };

    loadA(0);
    cvtStoreA(0, 0);
    __syncthreads();

    const int kg = lane >> 4, rw = lane & 15;
    for (int c = 0; c < NCH; c++) {
        const int buf = c & 1;
        if (c + 1 < NCH) loadA(c + 1);        // next A chunk: loads in flight

        short8v ah[2], al[2];
#pragma unroll
        for (int rt = 0; rt < 2; rt++) {
            ah[rt] = *(const short8v*)&A_lds[buf][0][rt][kg][rw][0];
            al[rt] = *(const short8v*)&A_lds[buf][1][rt][kg][rw][0];
        }

        const size_t fb0 = ((size_t)(c * CT + wv * CTW)) * 512 + (size_t)lane * 8;
        short8v wh = *(const short8v*)(WF + fb0);
        short8v wl = *(const short8v*)(WF + fstride + fb0);
#pragma unroll
        for (int t = 0; t < CTW; t++) {
            short8v nwh, nwl;
            if (t + 1 < CTW) {                // prefetch next col-tile's W
                const size_t fb = fb0 + (size_t)(t + 1) * 512;
                nwh = *(const short8v*)(WF + fb);
                nwl = *(const short8v*)(WF + fstride + fb);
            }
            __builtin_amdgcn_s_setprio(1);
#pragma unroll
            for (int rt = 0; rt < 2; rt++) {
                acc[rt][t] = __builtin_amdgcn_mfma_f32_16x16x32_bf16(ah[rt], wh, acc[rt][t], 0, 0, 0);
                acc[rt][t] = __builtin_amdgcn_mfma_f32_16x16x32_bf16(al[rt], wh, acc[rt][t], 0, 0, 0);
                acc[rt][t] = __builtin_amdgcn_mfma_f32_16x16x32_bf16(ah[rt], wl, acc[rt][t], 0, 0, 0);
            }
            __builtin_amdgcn_s_setprio(0);
            if (t + 1 < CTW) { wh = nwh; wl = nwl; }
        }

        if (c + 1 < NCH) cvtStoreA((c + 1) & 1, c + 1);  // write other buffer
        __syncthreads();                       // single barrier per chunk
    }

    // ---- epilogue: bias, relu, store, stats ----
    const int mg = lane >> 4, colb = lane & 15;
#pragma unroll
    for (int t = 0; t < CTW; t++) {
        const int ct = wv * CTW + t;
        const int n = ct * 16 + colb;
        const float bn = (ACT && n < N) ? B[n] : 0.0f;
        float psum = 0.0f, psq = 0.0f;
#pragma unroll
        for (int rt = 0; rt < 2; rt++) {
#pragma unroll
            for (int j = 0; j < 4; j++) {
                int m = node0 + rt * 16 + mg * 4 + j;
                float vv = ACT ? fmaxf(acc[rt][t][j] + bn, 0.0f) : acc[rt][t][j];
                if (m < NODES && n < N) {
                    OUT[(size_t)m * opitch + n] = vv;
                    if (STATS) { psum += vv; psq += vv * vv; }
                }
            }
        }
        if (STATS && n < N) {
            atomicAdd(&shSum[n], psum);
            atomicAdd(&shSq[n], psq);
        }
    }
    if (STATS) {
        __syncthreads();
        for (int n = tid; n < N; n += 256) {
            atomicAdd(&gsum[n], shSum[n]);
            atomicAdd(&gsq[n], shSq[n]);
        }
    }
}

// ---------------------------------------------------------------------------
// BN finalize (scale/shift for folded apply)
// ---------------------------------------------------------------------------
template<int N>
__global__ void bn_finalize(const float* __restrict__ sum, const float* __restrict__ sq,
                            const float* __restrict__ gamma, const float* __restrict__ beta,
                            float* __restrict__ scale, float* __restrict__ shift) {
    int n = threadIdx.x;
    if (n < N) {
        float mean = sum[n] * (1.0f / NODES);
        float var  = sq[n] * (1.0f / NODES) - mean * mean;
        var = var < 0.0f ? 0.0f : var;
        float sc = gamma[n] * rsqrtf(var + 1e-5f);
        scale[n] = sc;
        shift[n] = beta[n] - mean * sc;
    }
}

// ---------------------------------------------------------------------------
// Pool (BN3 affine folded; h compact pitch 32) + head MLP
// ---------------------------------------------------------------------------
__global__ void pool_kernel(const float* __restrict__ h, const int* __restrict__ batch,
                            const float* __restrict__ scale, const float* __restrict__ shift,
                            float* __restrict__ g) {
    int idx = blockIdx.x * blockDim.x + threadIdx.x;
    if (idx >= NODES * 32) return;
    int n = idx >> 5, f = idx & 31;
    float v = fmaf(h[(size_t)n * 32 + f], scale[f], shift[f]);
    atomicAdd(&g[batch[n] * 32 + f], v);
}

__global__ void head_kernel(const float* __restrict__ g,
                            const float* __restrict__ fw1, const float* __restrict__ fb1,
                            const float* __restrict__ fw2, const float* __restrict__ fb2,
                            const float* __restrict__ ow, const float* __restrict__ ob,
                            float* __restrict__ out) {
    int gi = blockIdx.x * blockDim.x + threadIdx.x;
    if (gi >= GRAPHS) return;
    float v[32];
#pragma unroll
    for (int k = 0; k < 32; k++) v[k] = g[gi * 32 + k];
    float a1[16];
#pragma unroll
    for (int o = 0; o < 16; o++) {
        float s = fb1[o];
#pragma unroll
        for (int k = 0; k < 32; k++) s = fmaf(v[k], fw1[k * 16 + o], s);
        a1[o] = s > 0.0f ? s : 0.0f;
    }
    float a2[8];
#pragma unroll
    for (int o = 0; o < 8; o++) {
        float s = fb2[o];
#pragma unroll
        for (int k = 0; k < 16; k++) s = fmaf(a1[k], fw2[k * 8 + o], s);
        a2[o] = s > 0.0f ? s : 0.0f;
    }
#pragma unroll
    for (int o = 0; o < 2; o++) {
        float s = ob[o];
#pragma unroll
        for (int k = 0; k < 8; k++) s = fmaf(a2[k], ow[k * 2 + o], s);
        out[gi * 2 + o] = s;
    }
}

// ---------------------------------------------------------------------------
extern "C" void kernel_launch(void* const* d_in, const int* in_sizes, int n_in,
                              void* d_out, int out_size, void* d_ws, size_t ws_size,
                              hipStream_t stream) {
    const float* x     = (const float*)d_in[0];
    const int*   ei    = (const int*)d_in[1];
    const int*   batch = (const int*)d_in[2];
    const float *w1a = (const float*)d_in[3],  *b1a = (const float*)d_in[4];
    const float *w1b = (const float*)d_in[5],  *b1b = (const float*)d_in[6];
    const float *g1  = (const float*)d_in[7],  *be1 = (const float*)d_in[8];
    const float *w2a = (const float*)d_in[9],  *b2a = (const float*)d_in[10];
    const float *w2b = (const float*)d_in[11], *b2b = (const float*)d_in[12];
    const float *g2  = (const float*)d_in[13], *be2 = (const float*)d_in[14];
    const float *w3a = (const float*)d_in[15], *b3a = (const float*)d_in[16];
    const float *w3b = (const float*)d_in[17], *b3b = (const float*)d_in[18];
    const float *g3  = (const float*)d_in[19], *be3 = (const float*)d_in[20];
    const float *fw1 = (const float*)d_in[21], *fb1 = (const float*)d_in[22];
    const float *fw2 = (const float*)d_in[23], *fb2 = (const float*)d_in[24];
    const float *ow  = (const float*)d_in[25], *ob  = (const float*)d_in[26];
    const int* src = ei;
    const int* dst = ei + EDGES;

    float* ws    = (float*)d_ws;
    float* b0    = ws;                                  // 50000 x 200
    float* b1    = ws + (size_t)NODES * P;              // 50000 x 200
    float* Y2    = b1;                                  // 50000 x 64 (compact, in b1)
    float* AG2   = b1 + (size_t)NODES * 64;             // 50000 x 64 (compact, in b1)
    float* Y3    = b1;                                  // 50000 x 32 (compact, in b1)
    float* AG3   = b1 + (size_t)NODES * 32;             // 50000 x 32 (compact, in b1)
    float* SUM   = ws + (size_t)2 * NODES * P;          // 256
    float* SQ    = SUM + 256;
    float* SCALE = SUM + 512;
    float* SHIFT = SUM + 768;
    float* G     = SUM + 1024;                          // 1024 x 32
    int*   deg      = (int*)(G + GRAPHS * 32);          // 50000
    int*   rowstart = deg + NODES;                      // 50001
    int*   cursor   = rowstart + NODES + 1;             // 50000
    int*   part     = cursor + NODES;                   // 256 (scan partials)
    int*   csrc     = part + 256;                       // 800000
    uintptr_t wfp = ((uintptr_t)(csrc + EDGES) + 15) & ~(uintptr_t)15;
    ushort* WF1 = (ushort*)wfp;                         // 2*4*16*512  = 65536
    ushort* WF2 = WF1 + 65536;                          // 2*7*16*512  = 114688
    ushort* WF3 = WF2 + 114688;                         // 2*7*4*512   = 28672
    ushort* WF4 = WF3 + 28672;                          // 2*2*4*512   = 8192
    ushort* WF5 = WF4 + 8192;                           // 2*2*4*512   = 8192
    ushort* WF6 = WF5 + 8192;                           // 2*1*4*512   = 4096
    float* out = (float*)d_out;

    const int GBR = (NODES + 31) / 32;       // 1563 gemm blocks (32-row)
    const int AB = (NODES * 64 + 255) / 256; // agg blocks (wave per node)
    const int EB = (EDGES + 255) / 256;

    // ---- weight conversion to MFMA fragment layout (once per launch) ----
    pad_w_mfma<<<(65536 + 255) / 256, 256, 0, stream>>>(w1a, 114, 198, 4, 16, WF1);
    pad_w_mfma<<<(114688 + 255) / 256, 256, 0, stream>>>(w1b, 198, 198, 7, 16, WF2);
    pad_w_mfma<<<(28672 + 255) / 256, 256, 0, stream>>>(w2a, 198, 64, 7, 4, WF3);
    pad_w_mfma<<<(8192 + 255) / 256, 256, 0, stream>>>(w2b, 64, 64, 2, 4, WF4);
    pad_w_mfma<<<(8192 + 255) / 256, 256, 0, stream>>>(w3a, 64, 32, 2, 4, WF5);
    pad_w_mfma<<<(4096 + 255) / 256, 256, 0, stream>>>(w3b, 32, 32, 1, 4, WF6);

    // ---- CSR build (shared by all 3 layers) ----
    hipMemsetAsync(deg, 0, NODES * sizeof(int), stream);
    hist_kernel<<<EB, 256, 0, stream>>>(dst, deg);
    scan_part<<<SCAN_NB, SCAN_BLK, 0, stream>>>(deg, part);
    scan_scan<<<1, SCAN_BLK, 0, stream>>>(part);
    scan_expand<<<SCAN_NB, SCAN_BLK, 0, stream>>>(deg, part, rowstart, cursor);
    scatter_kernel<<<EB, 256, 0, stream>>>(src, dst, cursor, csrc);

    // ---- layer 1 (114 -> 198 -> 198): aggregate-first (dim expands) ----
    csr_agg<114><<<AB, 256, 0, stream>>>(x, 114, rowstart, csrc, b0, P);
    gemm_mfma<114, 198, true, false, false, false, true><<<GBR, 256, 0, stream>>>(
        x, 114, b0, P, WF1, b1a, nullptr, nullptr, nullptr, b1, P, nullptr, nullptr);
    hipMemsetAsync(SUM, 0, 512 * sizeof(float), stream);
    gemm_mfma<198, 198, false, true, false, false, true><<<GBR, 256, 0, stream>>>(
        b1, P, nullptr, 0, WF2, b1b, nullptr, nullptr, nullptr, b0, P, SUM, SQ);
    bn_finalize<198><<<1, 256, 0, stream>>>(SUM, SQ, g1, be1, SCALE, SHIFT);

    // ---- layer 2 (198 -> 64 -> 64): aggregate-after at D=64 ----
    gemm_mfma<198, 64, false, false, true, false, false><<<GBR, 256, 0, stream>>>(
        b0, P, nullptr, 0, WF3, nullptr, nullptr, SCALE, SHIFT, Y2, 64, nullptr, nullptr);
    csr_agg<64><<<AB, 256, 0, stream>>>(Y2, 64, rowstart, csrc, AG2, 64);
    hipMemsetAsync(SUM, 0, 512 * sizeof(float), stream);
    gemm_mfma<64, 64, true, true, false, true, true><<<GBR, 256, 0, stream>>>(
        Y2, 64, AG2, 64, WF4, b2b, b2a, nullptr, nullptr, b0, 64, SUM, SQ);
    bn_finalize<64><<<1, 256, 0, stream>>>(SUM, SQ, g2, be2, SCALE, SHIFT);

    // ---- layer 3 (64 -> 32 -> 32): aggregate-after at D=32 ----
    gemm_mfma<64, 32, false, false, true, false, false><<<GBR, 256, 0, stream>>>(
        b0, 64, nullptr, 0, WF5, nullptr, nullptr, SCALE, SHIFT, Y3, 32, nullptr, nullptr);
    csr_agg<32><<<AB, 256, 0, stream>>>(Y3, 32, rowstart, csrc, AG3, 32);
    hipMemsetAsync(SUM, 0, 512 * sizeof(float), stream);
    gemm_mfma<32, 32, true, true, false, true, true><<<GBR, 256, 0, stream>>>(
        Y3, 32, AG3, 32, WF6, b3b, b3a, nullptr, nullptr, b0, 32, SUM, SQ);
    bn_finalize<32><<<1, 256, 0, stream>>>(SUM, SQ, g3, be3, SCALE, SHIFT);

    // ---- pool (BN3 folded, pitch 32) + head ----
    hipMemsetAsync(G, 0, GRAPHS * 32 * sizeof(float), stream);
    pool_kernel<<<(NODES * 32 + 255) / 256, 256, 0, stream>>>(b0, batch, SCALE, SHIFT, G);
    head_kernel<<<(GRAPHS + 255) / 256, 256, 0, stream>>>(G, fw1, fb1, fw2, fb2, ow, ob, out);
}